// Round 1
// baseline (20415.141 us; speedup 1.0000x reference)
//
#include <hip/hip_runtime.h>
#include <hip/hip_bf16.h>

#define UNITS 400
#define GATES (4*UNITS)   // 1600
#define TLEN  1000
#define BATCH 64
#define BLOCK 512         // 8 waves; threads 0..399 own one float4 column-group

__device__ __forceinline__ float sigmoid_(float x) {
    return 1.0f / (1.0f + __expf(-x));
}
__device__ __forceinline__ float tanh_(float x) {
    // tanh(x) = 1 - 2/(exp(2x)+1)  — saturates correctly for large |x|
    return 1.0f - 2.0f / (__expf(2.0f * x) + 1.0f);
}

__global__ __launch_bounds__(BLOCK) void lstm_fused(
    const float* __restrict__ x,      // [B,T,3]
    const float* __restrict__ W_x,    // [3,1600]
    const float* __restrict__ W_h,    // [400,1600]
    const float* __restrict__ bvec,   // [1600]
    const float* __restrict__ p_i,    // [400]
    const float* __restrict__ p_f,    // [400]
    const float* __restrict__ p_o,    // [400]
    const float* __restrict__ W_out,  // [400,3]
    const float* __restrict__ b_out,  // [3]
    float* __restrict__ out)          // [B,T,3]
{
    const int b    = blockIdx.x;
    const int tid  = threadIdx.x;
    const int lane = tid & 63;
    const int wv   = tid >> 6;

    __shared__ float hsh[UNITS];
    __shared__ float csh[UNITS];
    __shared__ float zsh[GATES];
    __shared__ float xb[3];
    __shared__ float red[BLOCK/64][3];

    const float4* Wh4 = (const float4*)W_h;   // [400 rows][400 float4-groups]
    const int g = tid;                        // column group (4 cols) if < 400

    // ---- hoist all t-invariant per-thread loads ----
    float4 wx0, wx1, wx2, bb;
    if (g < GATES/4) {
        const float4* Wx4 = (const float4*)W_x;
        wx0 = Wx4[0*400 + g];
        wx1 = Wx4[1*400 + g];
        wx2 = Wx4[2*400 + g];
        bb  = ((const float4*)bvec)[g];
    }
    float piu = 0.f, pfu = 0.f, pou = 0.f, wo0 = 0.f, wo1 = 0.f, wo2 = 0.f;
    if (tid < UNITS) {
        piu = p_i[tid]; pfu = p_f[tid]; pou = p_o[tid];
        wo0 = W_out[tid*3+0]; wo1 = W_out[tid*3+1]; wo2 = W_out[tid*3+2];
        hsh[tid] = 0.f;
        csh[tid] = 0.f;
    }
    const float bo = (tid < 3) ? b_out[tid] : 0.f;

    const float* xrow = x   + (size_t)b * TLEN * 3;
    float*       orow = out + (size_t)b * TLEN * 3;

    for (int t = 0; t < TLEN; ++t) {
        // ---- A: stage x_t ----
        if (tid < 3) xb[tid] = xrow[t*3 + tid];
        __syncthreads();   // xb ready; h from previous step ready
        const float x0 = xb[0], x1 = xb[1], x2 = xb[2];

        // ---- C: z = x_t@W_x + b + h@W_h   (each thread: 4 columns) ----
        if (g < GATES/4) {
            float4 acc;
            acc.x = fmaf(x0, wx0.x, fmaf(x1, wx1.x, fmaf(x2, wx2.x, bb.x)));
            acc.y = fmaf(x0, wx0.y, fmaf(x1, wx1.y, fmaf(x2, wx2.y, bb.y)));
            acc.z = fmaf(x0, wx0.z, fmaf(x1, wx1.z, fmaf(x2, wx2.z, bb.z)));
            acc.w = fmaf(x0, wx0.w, fmaf(x1, wx1.w, fmaf(x2, wx2.w, bb.w)));
            const float4* wp = Wh4 + g;
            #pragma unroll 8
            for (int k = 0; k < UNITS; ++k) {
                const float  hk = hsh[k];
                const float4 w  = wp[(size_t)k * 400];
                acc.x = fmaf(hk, w.x, acc.x);
                acc.y = fmaf(hk, w.y, acc.y);
                acc.z = fmaf(hk, w.z, acc.z);
                acc.w = fmaf(hk, w.w, acc.w);
            }
            ((float4*)zsh)[g] = acc;
        }
        __syncthreads();   // z ready

        // ---- E: gates + state update + partial output ----
        float s0 = 0.f, s1 = 0.f, s2 = 0.f;
        if (tid < UNITS) {
            const float cc = csh[tid];
            const float zi = zsh[tid];
            const float zf = zsh[tid +   UNITS];
            const float zg = zsh[tid + 2*UNITS];
            const float zo = zsh[tid + 3*UNITS];
            const float ig = sigmoid_(fmaf(piu, cc, zi));
            const float fg = sigmoid_(fmaf(pfu, cc, zf));
            const float gg = tanh_(zg);
            const float cn = fmaf(fg, cc, ig * gg);
            const float og = sigmoid_(fmaf(pou, cn, zo));
            const float hn = og * tanh_(cn);
            csh[tid] = cn;
            hsh[tid] = hn;
            s0 = hn * wo0; s1 = hn * wo1; s2 = hn * wo2;
        }
        // wave-level reduction (width 64)
        #pragma unroll
        for (int off = 32; off; off >>= 1) {
            s0 += __shfl_down(s0, off);
            s1 += __shfl_down(s1, off);
            s2 += __shfl_down(s2, off);
        }
        if (lane == 0) { red[wv][0] = s0; red[wv][1] = s1; red[wv][2] = s2; }
        __syncthreads();   // red ready; h/c ready for next step

        // ---- G: final output for this timestep ----
        if (tid < 3) {
            float r = bo;
            #pragma unroll
            for (int w2 = 0; w2 < BLOCK/64; ++w2) r += red[w2][tid];
            orow[t*3 + tid] = r;
        }
    }
}

extern "C" void kernel_launch(void* const* d_in, const int* in_sizes, int n_in,
                              void* d_out, int out_size, void* d_ws, size_t ws_size,
                              hipStream_t stream) {
    const float* x     = (const float*)d_in[0];
    const float* W_x   = (const float*)d_in[1];
    const float* W_h   = (const float*)d_in[2];
    const float* b     = (const float*)d_in[3];
    const float* p_i   = (const float*)d_in[4];
    const float* p_f   = (const float*)d_in[5];
    const float* p_o   = (const float*)d_in[6];
    const float* W_out = (const float*)d_in[7];
    const float* b_out = (const float*)d_in[8];

    lstm_fused<<<BATCH, BLOCK, 0, stream>>>(
        x, W_x, W_h, b, p_i, p_f, p_o, W_out, b_out, (float*)d_out);
}

// Round 2
// 14292.140 us; speedup vs baseline: 1.4284x; 1.4284x over previous
//
#include <hip/hip_runtime.h>
#include <hip/hip_bf16.h>
#include <stdint.h>

#define UNITS 400
#define GATES 1600
#define TLEN  1000
#define BATCH 64

#define NBLK 16        // blocks per group (weight slices)
#define NGRP 16        // groups
#define BPG  4         // batches per group
#define UPB  25        // units per block
#define CPB  100       // cols per block = UPB*4 gates
#define KK   20        // k-split factor
#define KCH  20        // k-chunk = UNITS/KK
#define KPAD 21        // padded kk stride (odd -> conflict-free LDS)

// d_ws layout
#define WBUF_OFF 0                                   // [NBLK][UNITS][CPB] f32 = 2,560,000 B
#define HBUF_OFF (NBLK*UNITS*CPB*4)                  // [2][BATCH][UNITS]  f32 =   204,800 B
#define CTR_OFF  (HBUF_OFF + 2*BATCH*UNITS*4)
#define CTR_STRIDE 32                                // u32 units (128 B apart)
#define WS_NEED  ((size_t)CTR_OFF + NGRP*CTR_STRIDE*4)

__device__ __forceinline__ float sigmoid_(float x) {
    return 1.0f / (1.0f + __expf(-x));
}
__device__ __forceinline__ float tanh_(float x) {
    return 1.0f - 2.0f / (__expf(2.0f * x) + 1.0f);
}

// ---- one-time weight reorder: wbuf[j][k][c] = W_h[k][(c/25)*400 + j*25 + c%25] ----
__global__ void reorder_w(const float* __restrict__ W_h, float* __restrict__ wbuf) {
    int i = blockIdx.x * 256 + threadIdx.x;
    if (i >= NBLK * UNITS * CPB) return;
    int c = i % CPB;
    int k = (i / CPB) % UNITS;
    int j = i / (CPB * UNITS);
    int g = c / UPB, u2 = c % UPB;
    int col = g * UNITS + j * UPB + u2;
    wbuf[i] = W_h[k * GATES + col];
}

// ---- main multi-block fused LSTM ----
__global__ __launch_bounds__(512, 1) void lstm_mb(
    const float* __restrict__ x,      // [B,T,3]
    const float* __restrict__ W_x,    // [3,1600]
    const float* __restrict__ bvec,   // [1600]
    const float* __restrict__ p_i,
    const float* __restrict__ p_f,
    const float* __restrict__ p_o,
    const float* __restrict__ W_out,  // [400,3]
    const float* __restrict__ b_out,  // [3]
    const float* __restrict__ wbuf,   // reordered W_h slices
    float*       __restrict__ hbuf,   // [2][B][U] exchange buffer
    unsigned int* __restrict__ ctr,   // [NGRP] padded barrier counters
    float*       __restrict__ out)    // [B,T,3]
{
    const int gr  = blockIdx.x / NBLK;
    const int j   = blockIdx.x % NBLK;
    const int tid = threadIdx.x;
    const int lane = tid & 63;
    const int wv   = tid >> 6;

    __shared__ float hsh[BPG][UNITS];          // 6.4 KB
    __shared__ float zpart[BPG][CPB][KPAD];    // 33.6 KB
    __shared__ float zsh[BPG][CPB];            // 1.6 KB
    __shared__ float csh[BPG][UPB];
    __shared__ float xsh[BPG][4];
    __shared__ float red[8][4];

    const float* wslice = wbuf + (size_t)j * UNITS * CPB;

    // ---- roles & t-invariant hoists ----
    // z-loop threads: tid < 500 : (kk = tid/25, cq = tid%25)
    const int kk = tid / 25, cq = tid % 25;
    const bool zrole = (tid < KK * 25);

    // reduce threads: tid < 400 : (rb = tid/100, rc = tid%100)
    const int rb = tid / CPB, rc = tid % CPB;
    float wx0 = 0.f, wx1 = 0.f, wx2 = 0.f, bbv = 0.f;
    if (tid < BPG * CPB) {
        int gcol = (rc / UPB) * UNITS + j * UPB + (rc % UPB);
        wx0 = W_x[0 * GATES + gcol];
        wx1 = W_x[1 * GATES + gcol];
        wx2 = W_x[2 * GATES + gcol];
        bbv = bvec[gcol];
    }

    // gate threads: tid < 100 : (gb = tid/25, gu = tid%25)
    const int gb = tid / UPB, gu = tid % UPB;
    float piu = 0.f, pfu = 0.f, pou = 0.f;
    int unit = 0;
    if (tid < BPG * UPB) {
        unit = j * UPB + gu;
        piu = p_i[unit]; pfu = p_f[unit]; pou = p_o[unit];
    }

    // y threads (blocks j<4): tid < 400 holds a W_out row
    float wo0 = 0.f, wo1 = 0.f, wo2 = 0.f;
    if (tid < UNITS) {
        wo0 = W_out[tid * 3 + 0];
        wo1 = W_out[tid * 3 + 1];
        wo2 = W_out[tid * 3 + 2];
    }
    const float bo = (tid < 3) ? b_out[tid] : 0.f;

    // ---- state init ----
    if (tid < UNITS) {
        #pragma unroll
        for (int b = 0; b < BPG; ++b) hsh[b][tid] = 0.f;
    }
    if (tid < BPG * UPB) csh[gb][gu] = 0.f;
    __syncthreads();

    unsigned int* myctr = ctr + gr * CTR_STRIDE;

    for (int t = 0; t < TLEN; ++t) {
        const int p = t & 1;

        // ---- stage x_t for the group's 4 batches ----
        if (tid < BPG * 3) {
            int b = tid / 3, f = tid % 3;
            xsh[b][f] = x[((size_t)(gr * BPG + b) * TLEN + t) * 3 + f];
        }

        // ---- z-loop: h @ W_h partials (k-split) ----
        if (zrole) {
            const int k0 = kk * KCH;
            const float4* wq = (const float4*)wslice + cq;  // quad cq of each k-row
            float4 a0 = {0,0,0,0}, a1 = a0, a2 = a0, a3 = a0;
            #pragma unroll
            for (int ko = 0; ko < KCH; ko += 4) {
                const float4 h0 = *(const float4*)&hsh[0][k0 + ko];
                const float4 h1 = *(const float4*)&hsh[1][k0 + ko];
                const float4 h2 = *(const float4*)&hsh[2][k0 + ko];
                const float4 h3 = *(const float4*)&hsh[3][k0 + ko];
                #pragma unroll
                for (int dk = 0; dk < 4; ++dk) {
                    const float4 w = wq[(size_t)(k0 + ko + dk) * (CPB/4)];
                    const float e0 = (dk==0)?h0.x:(dk==1)?h0.y:(dk==2)?h0.z:h0.w;
                    const float e1 = (dk==0)?h1.x:(dk==1)?h1.y:(dk==2)?h1.z:h1.w;
                    const float e2 = (dk==0)?h2.x:(dk==1)?h2.y:(dk==2)?h2.z:h2.w;
                    const float e3 = (dk==0)?h3.x:(dk==1)?h3.y:(dk==2)?h3.z:h3.w;
                    a0.x = fmaf(e0, w.x, a0.x); a0.y = fmaf(e0, w.y, a0.y);
                    a0.z = fmaf(e0, w.z, a0.z); a0.w = fmaf(e0, w.w, a0.w);
                    a1.x = fmaf(e1, w.x, a1.x); a1.y = fmaf(e1, w.y, a1.y);
                    a1.z = fmaf(e1, w.z, a1.z); a1.w = fmaf(e1, w.w, a1.w);
                    a2.x = fmaf(e2, w.x, a2.x); a2.y = fmaf(e2, w.y, a2.y);
                    a2.z = fmaf(e2, w.z, a2.z); a2.w = fmaf(e2, w.w, a2.w);
                    a3.x = fmaf(e3, w.x, a3.x); a3.y = fmaf(e3, w.y, a3.y);
                    a3.z = fmaf(e3, w.z, a3.z); a3.w = fmaf(e3, w.w, a3.w);
                }
            }
            const int cb = cq * 4;
            zpart[0][cb+0][kk] = a0.x; zpart[0][cb+1][kk] = a0.y;
            zpart[0][cb+2][kk] = a0.z; zpart[0][cb+3][kk] = a0.w;
            zpart[1][cb+0][kk] = a1.x; zpart[1][cb+1][kk] = a1.y;
            zpart[1][cb+2][kk] = a1.z; zpart[1][cb+3][kk] = a1.w;
            zpart[2][cb+0][kk] = a2.x; zpart[2][cb+1][kk] = a2.y;
            zpart[2][cb+2][kk] = a2.z; zpart[2][cb+3][kk] = a2.w;
            zpart[3][cb+0][kk] = a3.x; zpart[3][cb+1][kk] = a3.y;
            zpart[3][cb+2][kk] = a3.z; zpart[3][cb+3][kk] = a3.w;
        }
        __syncthreads();

        // ---- reduce k-partials + x-projection -> z ----
        if (tid < BPG * CPB) {
            float s = fmaf(xsh[rb][0], wx0,
                      fmaf(xsh[rb][1], wx1,
                      fmaf(xsh[rb][2], wx2, bbv)));
            #pragma unroll
            for (int q = 0; q < KK; ++q) s += zpart[rb][rc][q];
            zsh[rb][rc] = s;
        }
        __syncthreads();

        // ---- gates + state update; publish h slice ----
        if (tid < BPG * UPB) {
            const float cc = csh[gb][gu];
            const float zi = zsh[gb][gu];
            const float zf = zsh[gb][UPB   + gu];
            const float zg = zsh[gb][2*UPB + gu];
            const float zo = zsh[gb][3*UPB + gu];
            const float ig = sigmoid_(fmaf(piu, cc, zi));
            const float fg = sigmoid_(fmaf(pfu, cc, zf));
            const float gg = tanh_(zg);
            const float cn = fmaf(fg, cc, ig * gg);
            const float og = sigmoid_(fmaf(pou, cn, zo));
            const float hn = og * tanh_(cn);
            csh[gb][gu] = cn;
            const int batch = gr * BPG + gb;
            __hip_atomic_store(&hbuf[(size_t)p * BATCH * UNITS + batch * UNITS + unit],
                               hn, __ATOMIC_RELEASE, __HIP_MEMORY_SCOPE_AGENT);
        }
        __syncthreads();   // all release-stores drained (syncthreads waits vmcnt)

        // ---- inter-block barrier (group of 16) ----
        if (tid == 0) {
            __hip_atomic_fetch_add(myctr, 1u, __ATOMIC_ACQ_REL, __HIP_MEMORY_SCOPE_AGENT);
            const unsigned target = (unsigned)NBLK * (unsigned)(t + 1);
            while (__hip_atomic_load(myctr, __ATOMIC_ACQUIRE, __HIP_MEMORY_SCOPE_AGENT) < target) {
                __builtin_amdgcn_s_sleep(1);
            }
        }
        __syncthreads();

        // ---- reload full h for the group's batches ----
        if (tid < UNITS) {
            #pragma unroll
            for (int b = 0; b < BPG; ++b)
                hsh[b][tid] = hbuf[(size_t)p * BATCH * UNITS + (gr * BPG + b) * UNITS + tid];
        }
        __syncthreads();

        // ---- output y_t: blocks j<4 each handle one batch of the group ----
        if (j < BPG) {
            float s0 = 0.f, s1 = 0.f, s2 = 0.f;
            if (tid < UNITS) {
                const float hv = hsh[j][tid];
                s0 = hv * wo0; s1 = hv * wo1; s2 = hv * wo2;
            }
            #pragma unroll
            for (int off = 32; off; off >>= 1) {
                s0 += __shfl_down(s0, off);
                s1 += __shfl_down(s1, off);
                s2 += __shfl_down(s2, off);
            }
            if (lane == 0) { red[wv][0] = s0; red[wv][1] = s1; red[wv][2] = s2; }
        }
        __syncthreads();
        if (j < BPG && tid < 3) {
            float r = bo;
            #pragma unroll
            for (int w2 = 0; w2 < 8; ++w2) r += red[w2][tid];
            out[((size_t)(gr * BPG + j) * TLEN + t) * 3 + tid] = r;
        }
    }
}

// ---- fallback: proven round-1 single-block-per-batch kernel ----
__global__ __launch_bounds__(512) void lstm_fused_fb(
    const float* __restrict__ x, const float* __restrict__ W_x,
    const float* __restrict__ W_h, const float* __restrict__ bvec,
    const float* __restrict__ p_i, const float* __restrict__ p_f,
    const float* __restrict__ p_o, const float* __restrict__ W_out,
    const float* __restrict__ b_out, float* __restrict__ out)
{
    const int b = blockIdx.x, tid = threadIdx.x;
    const int lane = tid & 63, wv = tid >> 6;
    __shared__ float hsh[UNITS], csh[UNITS], zsh[GATES], xb[3], red[8][3];
    const float4* Wh4 = (const float4*)W_h;
    const int g = tid;
    float4 wx0, wx1, wx2, bb;
    if (g < GATES/4) {
        const float4* Wx4 = (const float4*)W_x;
        wx0 = Wx4[0*400 + g]; wx1 = Wx4[1*400 + g]; wx2 = Wx4[2*400 + g];
        bb  = ((const float4*)bvec)[g];
    }
    float piu=0.f,pfu=0.f,pou=0.f,wo0=0.f,wo1=0.f,wo2=0.f;
    if (tid < UNITS) {
        piu=p_i[tid]; pfu=p_f[tid]; pou=p_o[tid];
        wo0=W_out[tid*3]; wo1=W_out[tid*3+1]; wo2=W_out[tid*3+2];
        hsh[tid]=0.f; csh[tid]=0.f;
    }
    const float bo = (tid<3)?b_out[tid]:0.f;
    const float* xrow = x + (size_t)b*TLEN*3;
    float* orow = out + (size_t)b*TLEN*3;
    for (int t=0;t<TLEN;++t){
        if (tid<3) xb[tid]=xrow[t*3+tid];
        __syncthreads();
        const float x0=xb[0],x1=xb[1],x2=xb[2];
        if (g < GATES/4){
            float4 acc;
            acc.x=fmaf(x0,wx0.x,fmaf(x1,wx1.x,fmaf(x2,wx2.x,bb.x)));
            acc.y=fmaf(x0,wx0.y,fmaf(x1,wx1.y,fmaf(x2,wx2.y,bb.y)));
            acc.z=fmaf(x0,wx0.z,fmaf(x1,wx1.z,fmaf(x2,wx2.z,bb.z)));
            acc.w=fmaf(x0,wx0.w,fmaf(x1,wx1.w,fmaf(x2,wx2.w,bb.w)));
            const float4* wp=Wh4+g;
            #pragma unroll 8
            for(int k=0;k<UNITS;++k){
                const float hk=hsh[k]; const float4 w=wp[(size_t)k*400];
                acc.x=fmaf(hk,w.x,acc.x); acc.y=fmaf(hk,w.y,acc.y);
                acc.z=fmaf(hk,w.z,acc.z); acc.w=fmaf(hk,w.w,acc.w);
            }
            ((float4*)zsh)[g]=acc;
        }
        __syncthreads();
        float s0=0.f,s1=0.f,s2=0.f;
        if (tid<UNITS){
            const float cc=csh[tid];
            const float zi=zsh[tid],zf=zsh[tid+UNITS],zg=zsh[tid+2*UNITS],zo=zsh[tid+3*UNITS];
            const float ig=sigmoid_(fmaf(piu,cc,zi));
            const float fg=sigmoid_(fmaf(pfu,cc,zf));
            const float gg=tanh_(zg);
            const float cn=fmaf(fg,cc,ig*gg);
            const float og=sigmoid_(fmaf(pou,cn,zo));
            const float hn=og*tanh_(cn);
            csh[tid]=cn; hsh[tid]=hn;
            s0=hn*wo0; s1=hn*wo1; s2=hn*wo2;
        }
        #pragma unroll
        for(int off=32;off;off>>=1){
            s0+=__shfl_down(s0,off); s1+=__shfl_down(s1,off); s2+=__shfl_down(s2,off);
        }
        if(lane==0){red[wv][0]=s0;red[wv][1]=s1;red[wv][2]=s2;}
        __syncthreads();
        if(tid<3){
            float r=bo;
            #pragma unroll
            for(int w2=0;w2<8;++w2) r+=red[w2][tid];
            orow[t*3+tid]=r;
        }
    }
}

extern "C" void kernel_launch(void* const* d_in, const int* in_sizes, int n_in,
                              void* d_out, int out_size, void* d_ws, size_t ws_size,
                              hipStream_t stream) {
    const float* x     = (const float*)d_in[0];
    const float* W_x   = (const float*)d_in[1];
    const float* W_h   = (const float*)d_in[2];
    const float* b     = (const float*)d_in[3];
    const float* p_i   = (const float*)d_in[4];
    const float* p_f   = (const float*)d_in[5];
    const float* p_o   = (const float*)d_in[6];
    const float* W_out = (const float*)d_in[7];
    const float* b_out = (const float*)d_in[8];
    float* out = (float*)d_out;

    if (ws_size < WS_NEED) {
        lstm_fused_fb<<<BATCH, 512, 0, stream>>>(x, W_x, W_h, b, p_i, p_f, p_o,
                                                 W_out, b_out, out);
        return;
    }

    uint8_t* ws = (uint8_t*)d_ws;
    float* wbuf = (float*)(ws + WBUF_OFF);
    float* hbuf = (float*)(ws + HBUF_OFF);
    unsigned int* ctr = (unsigned int*)(ws + CTR_OFF);

    hipMemsetAsync(ctr, 0, NGRP * CTR_STRIDE * 4, stream);
    reorder_w<<<(NBLK * UNITS * CPB + 255) / 256, 256, 0, stream>>>(W_h, wbuf);
    lstm_mb<<<NGRP * NBLK, 512, 0, stream>>>(x, W_x, b, p_i, p_f, p_o,
                                             W_out, b_out, wbuf, hbuf, ctr, out);
}

// Round 3
// 12210.876 us; speedup vs baseline: 1.6719x; 1.1704x over previous
//
#include <hip/hip_runtime.h>
#include <hip/hip_bf16.h>
#include <stdint.h>

#define UNITS 400
#define GATES 1600
#define TLEN  1000
#define BATCH 64

#define NBLK 16        // blocks per group (weight slices)
#define NGRP 16        // groups (XCD-local under round-robin dispatch)
#define BPG  4         // batches per group
#define UPB  25        // units per block
#define CPB  100       // cols per block = UPB*4 gates
#define KK   20        // k-split factor (threads 0..499 are z-role)
#define KCH  20        // k-chunk = UNITS/KK  -> 20 float4 weight regs/thread

// d_ws layout
#define WBUF_OFF 0                                   // [NBLK][UNITS][CPB] f32 = 2,560,000 B
#define HBUF_OFF (NBLK*UNITS*CPB*4)                  // [2][BATCH][UNITS]  f32 =   204,800 B
#define CTR_OFF  (HBUF_OFF + 2*BATCH*UNITS*4)
#define CTR_STRIDE 32                                // u32 units (128 B apart)
#define WS_NEED  ((size_t)CTR_OFF + NGRP*CTR_STRIDE*4)

__device__ __forceinline__ float sigmoid_(float x) {
    return 1.0f / (1.0f + __expf(-x));
}
__device__ __forceinline__ float tanh_(float x) {
    return 1.0f - 2.0f / (__expf(2.0f * x) + 1.0f);
}

// ---- one-time weight reorder: wbuf[j][k][c] = W_h[k][(c/25)*400 + j*25 + c%25] ----
__global__ void reorder_w(const float* __restrict__ W_h, float* __restrict__ wbuf) {
    int i = blockIdx.x * 256 + threadIdx.x;
    if (i >= NBLK * UNITS * CPB) return;
    int c = i % CPB;
    int k = (i / CPB) % UNITS;
    int j = i / (CPB * UNITS);
    int g = c / UPB, u2 = c % UPB;
    int col = g * UNITS + j * UPB + u2;
    wbuf[i] = W_h[k * GATES + col];
}

// ---- main multi-block fused LSTM, register-resident weights ----
__global__ __launch_bounds__(512, 1) void lstm_mb(
    const float* __restrict__ x,      // [B,T,3]
    const float* __restrict__ W_x,    // [3,1600]
    const float* __restrict__ bvec,   // [1600]
    const float* __restrict__ p_i,
    const float* __restrict__ p_f,
    const float* __restrict__ p_o,
    const float* __restrict__ W_out,  // [400,3]
    const float* __restrict__ b_out,  // [3]
    const float* __restrict__ wbuf,   // reordered W_h slices
    float*       __restrict__ hbuf,   // [2][B][U] exchange buffer
    unsigned int* __restrict__ ctr,   // [NGRP] padded barrier counters
    float*       __restrict__ out)    // [B,T,3]
{
    // XCD-local group mapping: blockIdx = j*NGRP + gr  ->  XCD = gr % 8
    const int gr  = blockIdx.x % NGRP;
    const int j   = blockIdx.x / NGRP;
    const int tid = threadIdx.x;
    const int lane = tid & 63;
    const int wv   = tid >> 6;

    __shared__ float hsh[BPG][UNITS];          // 6.4 KB
    __shared__ float zpart[KK][BPG][CPB];      // 32 KB   (float4-write friendly)
    __shared__ float zsh[BPG][CPB];            // 1.6 KB
    __shared__ float csh[BPG][UPB];
    __shared__ float xsh[BPG][4];
    __shared__ float red[8][4];

    const float* wslice = wbuf + (size_t)j * UNITS * CPB;

    // ---- roles ----
    const int kk = tid / 25, cq = tid % 25;       // z-role: tid < 500
    const bool zrole = (tid < KK * 25);
    const int k0 = kk * KCH;

    const int rb = tid / CPB, rc = tid % CPB;     // reduce-role: tid < 400
    const int gb = tid / UPB, gu = tid % UPB;     // gate-role: tid < 100

    // ---- register-resident weight patch: 20 x float4 (static indexing only) ----
    float4 wreg[KCH];
    if (zrole) {
        #pragma unroll
        for (int r = 0; r < KCH; ++r)
            wreg[r] = *(const float4*)&wslice[(size_t)(k0 + r) * CPB + cq * 4];
    }

    // ---- t-invariant hoists ----
    float wx0 = 0.f, wx1 = 0.f, wx2 = 0.f, bbv = 0.f;
    if (tid < BPG * CPB) {
        int gcol = (rc / UPB) * UNITS + j * UPB + (rc % UPB);
        wx0 = W_x[0 * GATES + gcol];
        wx1 = W_x[1 * GATES + gcol];
        wx2 = W_x[2 * GATES + gcol];
        bbv = bvec[gcol];
    }
    float piu = 0.f, pfu = 0.f, pou = 0.f;
    int unit = 0;
    if (tid < BPG * UPB) {
        unit = j * UPB + gu;
        piu = p_i[unit]; pfu = p_f[unit]; pou = p_o[unit];
    }
    float wo0 = 0.f, wo1 = 0.f, wo2 = 0.f;
    if (tid < UNITS) {
        wo0 = W_out[tid * 3 + 0];
        wo1 = W_out[tid * 3 + 1];
        wo2 = W_out[tid * 3 + 2];
    }
    const float bo = (tid < 3) ? b_out[tid] : 0.f;

    // ---- state init ----
    if (tid < UNITS) {
        #pragma unroll
        for (int b = 0; b < BPG; ++b) hsh[b][tid] = 0.f;
    }
    if (tid < BPG * UPB) csh[gb][gu] = 0.f;
    __syncthreads();

    unsigned int* myctr = ctr + gr * CTR_STRIDE;

    for (int t = 0; t < TLEN; ++t) {
        const int p = t & 1;

        // ---- stage x_t for the group's 4 batches ----
        if (tid < BPG * 3) {
            int b = tid / 3, f = tid % 3;
            xsh[b][f] = x[((size_t)(gr * BPG + b) * TLEN + t) * 3 + f];
        }

        // ---- z-loop: h @ W_h partials from register weights ----
        if (zrole) {
            float4 a0 = {0,0,0,0}, a1 = a0, a2 = a0, a3 = a0;
            #pragma unroll
            for (int ro = 0; ro < KCH; ro += 4) {
                const float4 h0 = *(const float4*)&hsh[0][k0 + ro];
                const float4 h1 = *(const float4*)&hsh[1][k0 + ro];
                const float4 h2 = *(const float4*)&hsh[2][k0 + ro];
                const float4 h3 = *(const float4*)&hsh[3][k0 + ro];
                #pragma unroll
                for (int dr = 0; dr < 4; ++dr) {
                    const float4 w = wreg[ro + dr];
                    const float e0 = (dr==0)?h0.x:(dr==1)?h0.y:(dr==2)?h0.z:h0.w;
                    const float e1 = (dr==0)?h1.x:(dr==1)?h1.y:(dr==2)?h1.z:h1.w;
                    const float e2 = (dr==0)?h2.x:(dr==1)?h2.y:(dr==2)?h2.z:h2.w;
                    const float e3 = (dr==0)?h3.x:(dr==1)?h3.y:(dr==2)?h3.z:h3.w;
                    a0.x = fmaf(e0, w.x, a0.x); a0.y = fmaf(e0, w.y, a0.y);
                    a0.z = fmaf(e0, w.z, a0.z); a0.w = fmaf(e0, w.w, a0.w);
                    a1.x = fmaf(e1, w.x, a1.x); a1.y = fmaf(e1, w.y, a1.y);
                    a1.z = fmaf(e1, w.z, a1.z); a1.w = fmaf(e1, w.w, a1.w);
                    a2.x = fmaf(e2, w.x, a2.x); a2.y = fmaf(e2, w.y, a2.y);
                    a2.z = fmaf(e2, w.z, a2.z); a2.w = fmaf(e2, w.w, a2.w);
                    a3.x = fmaf(e3, w.x, a3.x); a3.y = fmaf(e3, w.y, a3.y);
                    a3.z = fmaf(e3, w.z, a3.z); a3.w = fmaf(e3, w.w, a3.w);
                }
            }
            // conflict-free float4 stores: lanes (cq) write consecutive 16B
            *(float4*)&zpart[kk][0][cq * 4] = a0;
            *(float4*)&zpart[kk][1][cq * 4] = a1;
            *(float4*)&zpart[kk][2][cq * 4] = a2;
            *(float4*)&zpart[kk][3][cq * 4] = a3;
        }
        __syncthreads();

        // ---- reduce k-partials + x-projection -> z ----
        if (tid < BPG * CPB) {
            float s = fmaf(xsh[rb][0], wx0,
                      fmaf(xsh[rb][1], wx1,
                      fmaf(xsh[rb][2], wx2, bbv)));
            #pragma unroll
            for (int q = 0; q < KK; ++q) s += zpart[q][rb][rc];
            zsh[rb][rc] = s;
        }
        __syncthreads();

        // ---- gates + state update; publish h slice ----
        if (tid < BPG * UPB) {
            const float cc = csh[gb][gu];
            const float zi = zsh[gb][gu];
            const float zf = zsh[gb][UPB   + gu];
            const float zg = zsh[gb][2*UPB + gu];
            const float zo = zsh[gb][3*UPB + gu];
            const float ig = sigmoid_(fmaf(piu, cc, zi));
            const float fg = sigmoid_(fmaf(pfu, cc, zf));
            const float gg = tanh_(zg);
            const float cn = fmaf(fg, cc, ig * gg);
            const float og = sigmoid_(fmaf(pou, cn, zo));
            const float hn = og * tanh_(cn);
            csh[gb][gu] = cn;
            const int batch = gr * BPG + gb;
            __hip_atomic_store(&hbuf[(size_t)p * BATCH * UNITS + batch * UNITS + unit],
                               hn, __ATOMIC_RELEASE, __HIP_MEMORY_SCOPE_AGENT);
        }
        __syncthreads();   // all release-stores drained (per-wave vmcnt(0))

        // ---- inter-block barrier (group of 16, XCD-local counter) ----
        if (tid == 0) {
            __hip_atomic_fetch_add(myctr, 1u, __ATOMIC_ACQ_REL, __HIP_MEMORY_SCOPE_AGENT);
            const unsigned target = (unsigned)NBLK * (unsigned)(t + 1);
            while (__hip_atomic_load(myctr, __ATOMIC_ACQUIRE, __HIP_MEMORY_SCOPE_AGENT) < target) {
                __builtin_amdgcn_s_sleep(1);
            }
        }
        __syncthreads();

        // ---- reload full h for the group's batches ----
        if (tid < UNITS) {
            #pragma unroll
            for (int b = 0; b < BPG; ++b)
                hsh[b][tid] = hbuf[(size_t)p * BATCH * UNITS + (gr * BPG + b) * UNITS + tid];
        }
        __syncthreads();

        // ---- output y_t: blocks j<4 each handle one batch of the group ----
        if (j < BPG) {
            float s0 = 0.f, s1 = 0.f, s2 = 0.f;
            if (tid < UNITS) {
                const float hv = hsh[j][tid];
                s0 = hv * wo0; s1 = hv * wo1; s2 = hv * wo2;
            }
            #pragma unroll
            for (int off = 32; off; off >>= 1) {
                s0 += __shfl_down(s0, off);
                s1 += __shfl_down(s1, off);
                s2 += __shfl_down(s2, off);
            }
            if (lane == 0) { red[wv][0] = s0; red[wv][1] = s1; red[wv][2] = s2; }
        }
        __syncthreads();
        if (j < BPG && tid < 3) {
            float r = bo;
            #pragma unroll
            for (int w2 = 0; w2 < 8; ++w2) r += red[w2][tid];
            out[((size_t)(gr * BPG + j) * TLEN + t) * 3 + tid] = r;
        }
    }
}

// ---- fallback: proven round-1 single-block-per-batch kernel ----
__global__ __launch_bounds__(512) void lstm_fused_fb(
    const float* __restrict__ x, const float* __restrict__ W_x,
    const float* __restrict__ W_h, const float* __restrict__ bvec,
    const float* __restrict__ p_i, const float* __restrict__ p_f,
    const float* __restrict__ p_o, const float* __restrict__ W_out,
    const float* __restrict__ b_out, float* __restrict__ out)
{
    const int b = blockIdx.x, tid = threadIdx.x;
    const int lane = tid & 63, wv = tid >> 6;
    __shared__ float hsh[UNITS], csh[UNITS], zsh[GATES], xb[3], red[8][3];
    const float4* Wh4 = (const float4*)W_h;
    const int g = tid;
    float4 wx0, wx1, wx2, bb;
    if (g < GATES/4) {
        const float4* Wx4 = (const float4*)W_x;
        wx0 = Wx4[0*400 + g]; wx1 = Wx4[1*400 + g]; wx2 = Wx4[2*400 + g];
        bb  = ((const float4*)bvec)[g];
    }
    float piu=0.f,pfu=0.f,pou=0.f,wo0=0.f,wo1=0.f,wo2=0.f;
    if (tid < UNITS) {
        piu=p_i[tid]; pfu=p_f[tid]; pou=p_o[tid];
        wo0=W_out[tid*3]; wo1=W_out[tid*3+1]; wo2=W_out[tid*3+2];
        hsh[tid]=0.f; csh[tid]=0.f;
    }
    const float bo = (tid<3)?b_out[tid]:0.f;
    const float* xrow = x + (size_t)b*TLEN*3;
    float* orow = out + (size_t)b*TLEN*3;
    for (int t=0;t<TLEN;++t){
        if (tid<3) xb[tid]=xrow[t*3+tid];
        __syncthreads();
        const float x0=xb[0],x1=xb[1],x2=xb[2];
        if (g < GATES/4){
            float4 acc;
            acc.x=fmaf(x0,wx0.x,fmaf(x1,wx1.x,fmaf(x2,wx2.x,bb.x)));
            acc.y=fmaf(x0,wx0.y,fmaf(x1,wx1.y,fmaf(x2,wx2.y,bb.y)));
            acc.z=fmaf(x0,wx0.z,fmaf(x1,wx1.z,fmaf(x2,wx2.z,bb.z)));
            acc.w=fmaf(x0,wx0.w,fmaf(x1,wx1.w,fmaf(x2,wx2.w,bb.w)));
            const float4* wp=Wh4+g;
            #pragma unroll 8
            for(int k=0;k<UNITS;++k){
                const float hk=hsh[k]; const float4 w=wp[(size_t)k*400];
                acc.x=fmaf(hk,w.x,acc.x); acc.y=fmaf(hk,w.y,acc.y);
                acc.z=fmaf(hk,w.z,acc.z); acc.w=fmaf(hk,w.w,acc.w);
            }
            ((float4*)zsh)[g]=acc;
        }
        __syncthreads();
        float s0=0.f,s1=0.f,s2=0.f;
        if (tid<UNITS){
            const float cc=csh[tid];
            const float zi=zsh[tid],zf=zsh[tid+UNITS],zg=zsh[tid+2*UNITS],zo=zsh[tid+3*UNITS];
            const float ig=sigmoid_(fmaf(piu,cc,zi));
            const float fg=sigmoid_(fmaf(pfu,cc,zf));
            const float gg=tanh_(zg);
            const float cn=fmaf(fg,cc,ig*gg);
            const float og=sigmoid_(fmaf(pou,cn,zo));
            const float hn=og*tanh_(cn);
            csh[tid]=cn; hsh[tid]=hn;
            s0=hn*wo0; s1=hn*wo1; s2=hn*wo2;
        }
        #pragma unroll
        for(int off=32;off;off>>=1){
            s0+=__shfl_down(s0,off); s1+=__shfl_down(s1,off); s2+=__shfl_down(s2,off);
        }
        if(lane==0){red[wv][0]=s0;red[wv][1]=s1;red[wv][2]=s2;}
        __syncthreads();
        if(tid<3){
            float r=bo;
            #pragma unroll
            for(int w2=0;w2<8;++w2) r+=red[w2][tid];
            orow[t*3+tid]=r;
        }
    }
}

extern "C" void kernel_launch(void* const* d_in, const int* in_sizes, int n_in,
                              void* d_out, int out_size, void* d_ws, size_t ws_size,
                              hipStream_t stream) {
    const float* x     = (const float*)d_in[0];
    const float* W_x   = (const float*)d_in[1];
    const float* W_h   = (const float*)d_in[2];
    const float* b     = (const float*)d_in[3];
    const float* p_i   = (const float*)d_in[4];
    const float* p_f   = (const float*)d_in[5];
    const float* p_o   = (const float*)d_in[6];
    const float* W_out = (const float*)d_in[7];
    const float* b_out = (const float*)d_in[8];
    float* out = (float*)d_out;

    if (ws_size < WS_NEED) {
        lstm_fused_fb<<<BATCH, 512, 0, stream>>>(x, W_x, W_h, b, p_i, p_f, p_o,
                                                 W_out, b_out, out);
        return;
    }

    uint8_t* ws = (uint8_t*)d_ws;
    float* wbuf = (float*)(ws + WBUF_OFF);
    float* hbuf = (float*)(ws + HBUF_OFF);
    unsigned int* ctr = (unsigned int*)(ws + CTR_OFF);

    hipMemsetAsync(ctr, 0, NGRP * CTR_STRIDE * 4, stream);
    reorder_w<<<(NBLK * UNITS * CPB + 255) / 256, 256, 0, stream>>>(W_h, wbuf);
    lstm_mb<<<NGRP * NBLK, 512, 0, stream>>>(x, W_x, b, p_i, p_f, p_o,
                                             W_out, b_out, wbuf, hbuf, ctr, out);
}

// Round 4
// 3794.177 us; speedup vs baseline: 5.3807x; 3.2183x over previous
//
#include <hip/hip_runtime.h>
#include <hip/hip_bf16.h>
#include <stdint.h>

#define UNITS 400
#define GATES 1600
#define TLEN  1000
#define BATCH 64

#define NBLK 16        // blocks per group (weight slices)
#define NGRP 16        // groups (XCD-local under round-robin dispatch — perf only)
#define BPG  4         // batches per group
#define UPB  25        // units per block
#define CPB  100       // cols per block = UPB*4 gates
#define KK   20        // k-split factor (threads 0..499 are z-role)
#define KCH  20        // k-chunk = UNITS/KK  -> 20 float4 weight regs/thread

// d_ws layout
#define WBUF_OFF 0                                   // [NBLK][UNITS][CPB] f32 = 2,560,000 B
#define HBUF_OFF (NBLK*UNITS*CPB*4)                  // [2][BATCH][UNITS]  f32 =   204,800 B
#define CTR_OFF  (HBUF_OFF + 2*BATCH*UNITS*4)
#define CTR_STRIDE 32                                // u32 units (128 B apart)
#define WS_NEED  ((size_t)CTR_OFF + NGRP*CTR_STRIDE*4)

__device__ __forceinline__ float sigmoid_(float x) {
    return 1.0f / (1.0f + __expf(-x));
}
__device__ __forceinline__ float tanh_(float x) {
    return 1.0f - 2.0f / (__expf(2.0f * x) + 1.0f);
}

// ---- one-time weight reorder: wbuf[j][k][c] = W_h[k][(c/25)*400 + j*25 + c%25] ----
__global__ void reorder_w(const float* __restrict__ W_h, float* __restrict__ wbuf) {
    int i = blockIdx.x * 256 + threadIdx.x;
    if (i >= NBLK * UNITS * CPB) return;
    int c = i % CPB;
    int k = (i / CPB) % UNITS;
    int j = i / (CPB * UNITS);
    int g = c / UPB, u2 = c % UPB;
    int col = g * UNITS + j * UPB + u2;
    wbuf[i] = W_h[k * GATES + col];
}

// ---- main multi-block fused LSTM, register weights + fence-free LLC exchange ----
__global__ __launch_bounds__(512, 1) void lstm_mb(
    const float* __restrict__ x,      // [B,T,3]
    const float* __restrict__ W_x,    // [3,1600]
    const float* __restrict__ bvec,   // [1600]
    const float* __restrict__ p_i,
    const float* __restrict__ p_f,
    const float* __restrict__ p_o,
    const float* __restrict__ W_out,  // [400,3]
    const float* __restrict__ b_out,  // [3]
    const float* __restrict__ wbuf,   // reordered W_h slices
    float*       __restrict__ hbuf,   // [2][B][U] exchange buffer
    unsigned int* __restrict__ ctr,   // [NGRP] padded barrier counters
    float*       __restrict__ out)    // [B,T,3]
{
    // XCD-local group mapping (performance heuristic only; protocol is
    // placement-independent): blockIdx = j*NGRP + gr  ->  all 16 blocks of a
    // group share blockIdx%8 -> same XCD under round-robin dispatch.
    const int gr  = blockIdx.x % NGRP;
    const int j   = blockIdx.x / NGRP;
    const int tid = threadIdx.x;
    const int lane = tid & 63;
    const int wv   = tid >> 6;

    __shared__ float hsh[BPG][UNITS];          // 6.4 KB
    __shared__ float zpart[KK][BPG][CPB];      // 32 KB
    __shared__ float zsh[BPG][CPB];            // 1.6 KB
    __shared__ float csh[BPG][UPB];
    __shared__ float xsh[BPG][4];
    __shared__ float red[8][4];

    const float* wslice = wbuf + (size_t)j * UNITS * CPB;

    // ---- roles ----
    const int kk = tid / 25, cq = tid % 25;       // z-role: tid < 500
    const bool zrole = (tid < KK * 25);
    const int k0 = kk * KCH;

    const int rb = tid / CPB, rc = tid % CPB;     // reduce-role: tid < 400
    const int gb = tid / UPB, gu = tid % UPB;     // gate-role: tid < 100

    // ---- register-resident weight patch: 20 x float4 (static indexing only) ----
    float4 wreg[KCH];
    if (zrole) {
        #pragma unroll
        for (int r = 0; r < KCH; ++r)
            wreg[r] = *(const float4*)&wslice[(size_t)(k0 + r) * CPB + cq * 4];
    }

    // ---- t-invariant hoists ----
    float wx0 = 0.f, wx1 = 0.f, wx2 = 0.f, bbv = 0.f;
    if (tid < BPG * CPB) {
        int gcol = (rc / UPB) * UNITS + j * UPB + (rc % UPB);
        wx0 = W_x[0 * GATES + gcol];
        wx1 = W_x[1 * GATES + gcol];
        wx2 = W_x[2 * GATES + gcol];
        bbv = bvec[gcol];
    }
    float piu = 0.f, pfu = 0.f, pou = 0.f;
    int unit = 0;
    if (tid < BPG * UPB) {
        unit = j * UPB + gu;
        piu = p_i[unit]; pfu = p_f[unit]; pou = p_o[unit];
    }
    float wo0 = 0.f, wo1 = 0.f, wo2 = 0.f;
    if (tid < UNITS) {
        wo0 = W_out[tid * 3 + 0];
        wo1 = W_out[tid * 3 + 1];
        wo2 = W_out[tid * 3 + 2];
    }
    const float bo = (tid < 3) ? b_out[tid] : 0.f;

    // ---- state init ----
    if (tid < UNITS) {
        #pragma unroll
        for (int b = 0; b < BPG; ++b) hsh[b][tid] = 0.f;
    }
    if (tid < BPG * UPB) csh[gb][gu] = 0.f;
    __syncthreads();

    unsigned int* myctr = ctr + gr * CTR_STRIDE;

    for (int t = 0; t < TLEN; ++t) {
        const int p = t & 1;

        // ---- stage x_t for the group's 4 batches ----
        if (tid < BPG * 3) {
            int b = tid / 3, f = tid % 3;
            xsh[b][f] = x[((size_t)(gr * BPG + b) * TLEN + t) * 3 + f];
        }

        // ---- z-loop: h @ W_h partials from register weights ----
        if (zrole) {
            float4 a0 = {0,0,0,0}, a1 = a0, a2 = a0, a3 = a0;
            #pragma unroll
            for (int ro = 0; ro < KCH; ro += 4) {
                const float4 h0 = *(const float4*)&hsh[0][k0 + ro];
                const float4 h1 = *(const float4*)&hsh[1][k0 + ro];
                const float4 h2 = *(const float4*)&hsh[2][k0 + ro];
                const float4 h3 = *(const float4*)&hsh[3][k0 + ro];
                #pragma unroll
                for (int dr = 0; dr < 4; ++dr) {
                    const float4 w = wreg[ro + dr];
                    const float e0 = (dr==0)?h0.x:(dr==1)?h0.y:(dr==2)?h0.z:h0.w;
                    const float e1 = (dr==0)?h1.x:(dr==1)?h1.y:(dr==2)?h1.z:h1.w;
                    const float e2 = (dr==0)?h2.x:(dr==1)?h2.y:(dr==2)?h2.z:h2.w;
                    const float e3 = (dr==0)?h3.x:(dr==1)?h3.y:(dr==2)?h3.z:h3.w;
                    a0.x = fmaf(e0, w.x, a0.x); a0.y = fmaf(e0, w.y, a0.y);
                    a0.z = fmaf(e0, w.z, a0.z); a0.w = fmaf(e0, w.w, a0.w);
                    a1.x = fmaf(e1, w.x, a1.x); a1.y = fmaf(e1, w.y, a1.y);
                    a1.z = fmaf(e1, w.z, a1.z); a1.w = fmaf(e1, w.w, a1.w);
                    a2.x = fmaf(e2, w.x, a2.x); a2.y = fmaf(e2, w.y, a2.y);
                    a2.z = fmaf(e2, w.z, a2.z); a2.w = fmaf(e2, w.w, a2.w);
                    a3.x = fmaf(e3, w.x, a3.x); a3.y = fmaf(e3, w.y, a3.y);
                    a3.z = fmaf(e3, w.z, a3.z); a3.w = fmaf(e3, w.w, a3.w);
                }
            }
            *(float4*)&zpart[kk][0][cq * 4] = a0;
            *(float4*)&zpart[kk][1][cq * 4] = a1;
            *(float4*)&zpart[kk][2][cq * 4] = a2;
            *(float4*)&zpart[kk][3][cq * 4] = a3;
        }
        __syncthreads();

        // ---- reduce k-partials + x-projection -> z ----
        if (tid < BPG * CPB) {
            float s = fmaf(xsh[rb][0], wx0,
                      fmaf(xsh[rb][1], wx1,
                      fmaf(xsh[rb][2], wx2, bbv)));
            #pragma unroll
            for (int q = 0; q < KK; ++q) s += zpart[q][rb][rc];
            zsh[rb][rc] = s;
        }
        __syncthreads();

        // ---- gates + state update; publish h slice (cache-bypass, no fence) ----
        if (tid < BPG * UPB) {
            const float cc = csh[gb][gu];
            const float zi = zsh[gb][gu];
            const float zf = zsh[gb][UPB   + gu];
            const float zg = zsh[gb][2*UPB + gu];
            const float zo = zsh[gb][3*UPB + gu];
            const float ig = sigmoid_(fmaf(piu, cc, zi));
            const float fg = sigmoid_(fmaf(pfu, cc, zf));
            const float gg = tanh_(zg);
            const float cn = fmaf(fg, cc, ig * gg);
            const float og = sigmoid_(fmaf(pou, cn, zo));
            const float hn = og * tanh_(cn);
            csh[gb][gu] = cn;
            const int batch = gr * BPG + gb;
            __hip_atomic_store(&hbuf[(size_t)p * BATCH * UNITS + batch * UNITS + unit],
                               hn, __ATOMIC_RELAXED, __HIP_MEMORY_SCOPE_AGENT);
        }
        // __syncthreads lowering drains vmcnt(0) per wave -> all publishes are
        // complete at the LLC before any thread proceeds. Ordering is
        // structural; no release fence needed.
        __syncthreads();

        // ---- inter-block barrier: relaxed RMW + relaxed polls (no invalidates) ----
        if (tid == 0) {
            __hip_atomic_fetch_add(myctr, 1u, __ATOMIC_RELAXED, __HIP_MEMORY_SCOPE_AGENT);
            const unsigned target = (unsigned)NBLK * (unsigned)(t + 1);
            while (__hip_atomic_load(myctr, __ATOMIC_RELAXED, __HIP_MEMORY_SCOPE_AGENT) < target) {
                __builtin_amdgcn_s_sleep(1);
            }
        }
        __syncthreads();

        // ---- reload full h (relaxed cache-bypass loads, coalesced dwords) ----
        if (tid < UNITS) {
            #pragma unroll
            for (int b = 0; b < BPG; ++b)
                hsh[b][tid] = __hip_atomic_load(
                    &hbuf[(size_t)p * BATCH * UNITS + (gr * BPG + b) * UNITS + tid],
                    __ATOMIC_RELAXED, __HIP_MEMORY_SCOPE_AGENT);
        }
        __syncthreads();

        // ---- output y_t: blocks j<4 each handle one batch of the group ----
        if (j < BPG) {
            float s0 = 0.f, s1 = 0.f, s2 = 0.f;
            if (tid < UNITS) {
                const float hv = hsh[j][tid];
                s0 = hv * wo0; s1 = hv * wo1; s2 = hv * wo2;
            }
            #pragma unroll
            for (int off = 32; off; off >>= 1) {
                s0 += __shfl_down(s0, off);
                s1 += __shfl_down(s1, off);
                s2 += __shfl_down(s2, off);
            }
            if (lane == 0) { red[wv][0] = s0; red[wv][1] = s1; red[wv][2] = s2; }
        }
        __syncthreads();
        if (j < BPG && tid < 3) {
            float r = bo;
            #pragma unroll
            for (int w2 = 0; w2 < 8; ++w2) r += red[w2][tid];
            out[((size_t)(gr * BPG + j) * TLEN + t) * 3 + tid] = r;
        }
    }
}

// ---- fallback: proven round-1 single-block-per-batch kernel ----
__global__ __launch_bounds__(512) void lstm_fused_fb(
    const float* __restrict__ x, const float* __restrict__ W_x,
    const float* __restrict__ W_h, const float* __restrict__ bvec,
    const float* __restrict__ p_i, const float* __restrict__ p_f,
    const float* __restrict__ p_o, const float* __restrict__ W_out,
    const float* __restrict__ b_out, float* __restrict__ out)
{
    const int b = blockIdx.x, tid = threadIdx.x;
    const int lane = tid & 63, wv = tid >> 6;
    __shared__ float hsh[UNITS], csh[UNITS], zsh[GATES], xb[3], red[8][3];
    const float4* Wh4 = (const float4*)W_h;
    const int g = tid;
    float4 wx0, wx1, wx2, bb;
    if (g < GATES/4) {
        const float4* Wx4 = (const float4*)W_x;
        wx0 = Wx4[0*400 + g]; wx1 = Wx4[1*400 + g]; wx2 = Wx4[2*400 + g];
        bb  = ((const float4*)bvec)[g];
    }
    float piu=0.f,pfu=0.f,pou=0.f,wo0=0.f,wo1=0.f,wo2=0.f;
    if (tid < UNITS) {
        piu=p_i[tid]; pfu=p_f[tid]; pou=p_o[tid];
        wo0=W_out[tid*3]; wo1=W_out[tid*3+1]; wo2=W_out[tid*3+2];
        hsh[tid]=0.f; csh[tid]=0.f;
    }
    const float bo = (tid<3)?b_out[tid]:0.f;
    const float* xrow = x + (size_t)b*TLEN*3;
    float* orow = out + (size_t)b*TLEN*3;
    for (int t=0;t<TLEN;++t){
        if (tid<3) xb[tid]=xrow[t*3+tid];
        __syncthreads();
        const float x0=xb[0],x1=xb[1],x2=xb[2];
        if (g < GATES/4){
            float4 acc;
            acc.x=fmaf(x0,wx0.x,fmaf(x1,wx1.x,fmaf(x2,wx2.x,bb.x)));
            acc.y=fmaf(x0,wx0.y,fmaf(x1,wx1.y,fmaf(x2,wx2.y,bb.y)));
            acc.z=fmaf(x0,wx0.z,fmaf(x1,wx1.z,fmaf(x2,wx2.z,bb.z)));
            acc.w=fmaf(x0,wx0.w,fmaf(x1,wx1.w,fmaf(x2,wx2.w,bb.w)));
            const float4* wp=Wh4+g;
            #pragma unroll 8
            for(int k=0;k<UNITS;++k){
                const float hk=hsh[k]; const float4 w=wp[(size_t)k*400];
                acc.x=fmaf(hk,w.x,acc.x); acc.y=fmaf(hk,w.y,acc.y);
                acc.z=fmaf(hk,w.z,acc.z); acc.w=fmaf(hk,w.w,acc.w);
            }
            ((float4*)zsh)[g]=acc;
        }
        __syncthreads();
        float s0=0.f,s1=0.f,s2=0.f;
        if (tid<UNITS){
            const float cc=csh[tid];
            const float zi=zsh[tid],zf=zsh[tid+UNITS],zg=zsh[tid+2*UNITS],zo=zsh[tid+3*UNITS];
            const float ig=sigmoid_(fmaf(piu,cc,zi));
            const float fg=sigmoid_(fmaf(pfu,cc,zf));
            const float gg=tanh_(zg);
            const float cn=fmaf(fg,cc,ig*gg);
            const float og=sigmoid_(fmaf(pou,cn,zo));
            const float hn=og*tanh_(cn);
            csh[tid]=cn; hsh[tid]=hn;
            s0=hn*wo0; s1=hn*wo1; s2=hn*wo2;
        }
        #pragma unroll
        for(int off=32;off;off>>=1){
            s0+=__shfl_down(s0,off); s1+=__shfl_down(s1,off); s2+=__shfl_down(s2,off);
        }
        if(lane==0){red[wv][0]=s0;red[wv][1]=s1;red[wv][2]=s2;}
        __syncthreads();
        if(tid<3){
            float r=bo;
            #pragma unroll
            for(int w2=0;w2<8;++w2) r+=red[w2][tid];
            orow[t*3+tid]=r;
        }
    }
}

extern "C" void kernel_launch(void* const* d_in, const int* in_sizes, int n_in,
                              void* d_out, int out_size, void* d_ws, size_t ws_size,
                              hipStream_t stream) {
    const float* x     = (const float*)d_in[0];
    const float* W_x   = (const float*)d_in[1];
    const float* W_h   = (const float*)d_in[2];
    const float* b     = (const float*)d_in[3];
    const float* p_i   = (const float*)d_in[4];
    const float* p_f   = (const float*)d_in[5];
    const float* p_o   = (const float*)d_in[6];
    const float* W_out = (const float*)d_in[7];
    const float* b_out = (const float*)d_in[8];
    float* out = (float*)d_out;

    if (ws_size < WS_NEED) {
        lstm_fused_fb<<<BATCH, 512, 0, stream>>>(x, W_x, W_h, b, p_i, p_f, p_o,
                                                 W_out, b_out, out);
        return;
    }

    uint8_t* ws = (uint8_t*)d_ws;
    float* wbuf = (float*)(ws + WBUF_OFF);
    float* hbuf = (float*)(ws + HBUF_OFF);
    unsigned int* ctr = (unsigned int*)(ws + CTR_OFF);

    hipMemsetAsync(ctr, 0, NGRP * CTR_STRIDE * 4, stream);
    reorder_w<<<(NBLK * UNITS * CPB + 255) / 256, 256, 0, stream>>>(W_h, wbuf);
    lstm_mb<<<NGRP * NBLK, 512, 0, stream>>>(x, W_x, b, p_i, p_f, p_o,
                                             W_out, b_out, wbuf, hbuf, ctr, out);
}

// Round 5
// 3565.268 us; speedup vs baseline: 5.7261x; 1.0642x over previous
//
#include <hip/hip_runtime.h>
#include <hip/hip_bf16.h>
#include <stdint.h>

#define UNITS 400
#define GATES 1600
#define TLEN  1000
#define BATCH 64

#define NBLK 16        // blocks per group (weight slices)
#define NGRP 16        // groups
#define BPG  4         // batches per group
#define UPB  25        // units per block
#define CPB  100       // cols per block = UPB*4 gates
#define KK   20        // k-split factor (threads 0..499 are z-role)
#define KCH  20        // k-chunk = UNITS/KK -> 20 float4 weight regs/thread
#define FLAG_STRIDE 32 // u32 units (128 B)

// d_ws layout
#define WBUF_OFF  0
#define WBUF_SZ   (NBLK*UNITS*CPB*4)                 // 2,560,000
#define HBUF_OFF  (WBUF_OFF + WBUF_SZ)
#define HBUF_SZ   (2*BATCH*UNITS*4)                  //   204,800
#define CTR_OFF   (HBUF_OFF + HBUF_SZ)
#define CTR_SZ    (NGRP*FLAG_STRIDE*4)               //     2,048
#define FLAGS_OFF (CTR_OFF + CTR_SZ)
#define FLAGS_SZ  (NGRP*NBLK*FLAG_STRIDE*4)          //    32,768
#define PART_OFF  (FLAGS_OFF + FLAGS_SZ)
#define PART_SZ   (NGRP*NBLK*BPG*3*TLEN*4)           // 12,288,000
#define WS_R4     ((size_t)FLAGS_OFF)                // counter-mode needs
#define WS_FULL   ((size_t)PART_OFF + PART_SZ)       // flag-mode needs

__device__ __forceinline__ float sigmoid_(float x) {
    return 1.0f / (1.0f + __expf(-x));
}
__device__ __forceinline__ float tanh_(float x) {
    return 1.0f - 2.0f / (__expf(2.0f * x) + 1.0f);
}

// ---- one-time weight reorder: wbuf[j][k][c] = W_h[k][(c/25)*400 + j*25 + c%25] ----
__global__ void reorder_w(const float* __restrict__ W_h, float* __restrict__ wbuf) {
    int i = blockIdx.x * 256 + threadIdx.x;
    if (i >= NBLK * UNITS * CPB) return;
    int c = i % CPB;
    int k = (i / CPB) % UNITS;
    int j = i / (CPB * UNITS);
    int g = c / UPB, u2 = c % UPB;
    int col = g * UNITS + j * UPB + u2;
    wbuf[i] = W_h[k * GATES + col];
}

// MODE 0: flag barrier + deferred y (needs part/flags). MODE 1: round-4 counter protocol.
template<int MODE>
__global__ __launch_bounds__(512, 1) void lstm_mb(
    const float* __restrict__ x,
    const float* __restrict__ W_x,
    const float* __restrict__ bvec,
    const float* __restrict__ p_i,
    const float* __restrict__ p_f,
    const float* __restrict__ p_o,
    const float* __restrict__ W_out,
    const float* __restrict__ b_out,
    const float* __restrict__ wbuf,
    float*       __restrict__ hbuf,      // [2][B][U]
    unsigned int* __restrict__ ctr,      // [NGRP] (MODE 1)
    unsigned int* __restrict__ flags,    // [NGRP*NBLK] padded (MODE 0)
    float*       __restrict__ part,      // [NGRP*NBLK][BPG][3][TLEN] (MODE 0)
    float*       __restrict__ out)
{
    const int gr  = blockIdx.x % NGRP;   // XCD-local heuristic (perf only)
    const int j   = blockIdx.x / NGRP;
    const int tid = threadIdx.x;
    const int lane = tid & 63;
    const int wv   = tid >> 6;

    __shared__ float hsh[BPG][UNITS];
    __shared__ float zpart[KK][BPG][CPB];
    __shared__ float zsh[BPG][CPB];
    __shared__ float csh[BPG][UPB];
    __shared__ float xsh[BPG][4];
    __shared__ float red[8][4];
    __shared__ float wosh[UPB][3];       // local W_out slice (MODE 0 partial-y)

    const float* wslice = wbuf + (size_t)j * UNITS * CPB;

    // ---- roles ----
    const int kk = tid / 25, cq = tid % 25;       // z-role: tid < 500
    const bool zrole = (tid < KK * 25);
    const int k0 = kk * KCH;
    const int rb = tid / CPB, rc = tid % CPB;     // reduce-role: tid < 400
    const int gb = tid / UPB, gu = tid % UPB;     // gate-role: tid < 100

    // ---- register-resident weight patch ----
    float4 wreg[KCH];
    if (zrole) {
        #pragma unroll
        for (int r = 0; r < KCH; ++r)
            wreg[r] = *(const float4*)&wslice[(size_t)(k0 + r) * CPB + cq * 4];
    }

    // ---- t-invariant hoists ----
    float wx0 = 0.f, wx1 = 0.f, wx2 = 0.f, bbv = 0.f;
    if (tid < BPG * CPB) {
        int gcol = (rc / UPB) * UNITS + j * UPB + (rc % UPB);
        wx0 = W_x[0 * GATES + gcol];
        wx1 = W_x[1 * GATES + gcol];
        wx2 = W_x[2 * GATES + gcol];
        bbv = bvec[gcol];
    }
    float piu = 0.f, pfu = 0.f, pou = 0.f;
    int unit = 0;
    if (tid < BPG * UPB) {
        unit = j * UPB + gu;
        piu = p_i[unit]; pfu = p_f[unit]; pou = p_o[unit];
    }
    float wo0 = 0.f, wo1 = 0.f, wo2 = 0.f;
    if (MODE == 1 && tid < UNITS) {
        wo0 = W_out[tid * 3 + 0];
        wo1 = W_out[tid * 3 + 1];
        wo2 = W_out[tid * 3 + 2];
    }
    const float bo = (tid < 3) ? b_out[tid] : 0.f;
    if (MODE == 0 && tid < UPB * 3) {
        wosh[tid / 3][tid % 3] = W_out[(j * UPB + tid / 3) * 3 + (tid % 3)];
    }

    // ---- state init ----
    if (tid < UNITS) {
        #pragma unroll
        for (int b = 0; b < BPG; ++b) hsh[b][tid] = 0.f;
    }
    if (tid < BPG * UPB) csh[gb][gu] = 0.f;
    __syncthreads();

    unsigned int* myctr = ctr + gr * FLAG_STRIDE;

    for (int t = 0; t < TLEN; ++t) {
        const int p = t & 1;

        // ---- stage x_t ----
        if (tid < BPG * 3) {
            int b = tid / 3, f = tid % 3;
            xsh[b][f] = x[((size_t)(gr * BPG + b) * TLEN + t) * 3 + f];
        }

        // ---- z-loop: h @ W_h partials from register weights ----
        if (zrole) {
            float4 a0 = {0,0,0,0}, a1 = a0, a2 = a0, a3 = a0;
            #pragma unroll
            for (int ro = 0; ro < KCH; ro += 4) {
                const float4 h0 = *(const float4*)&hsh[0][k0 + ro];
                const float4 h1 = *(const float4*)&hsh[1][k0 + ro];
                const float4 h2 = *(const float4*)&hsh[2][k0 + ro];
                const float4 h3 = *(const float4*)&hsh[3][k0 + ro];
                #pragma unroll
                for (int dr = 0; dr < 4; ++dr) {
                    const float4 w = wreg[ro + dr];
                    const float e0 = (dr==0)?h0.x:(dr==1)?h0.y:(dr==2)?h0.z:h0.w;
                    const float e1 = (dr==0)?h1.x:(dr==1)?h1.y:(dr==2)?h1.z:h1.w;
                    const float e2 = (dr==0)?h2.x:(dr==1)?h2.y:(dr==2)?h2.z:h2.w;
                    const float e3 = (dr==0)?h3.x:(dr==1)?h3.y:(dr==2)?h3.z:h3.w;
                    a0.x = fmaf(e0, w.x, a0.x); a0.y = fmaf(e0, w.y, a0.y);
                    a0.z = fmaf(e0, w.z, a0.z); a0.w = fmaf(e0, w.w, a0.w);
                    a1.x = fmaf(e1, w.x, a1.x); a1.y = fmaf(e1, w.y, a1.y);
                    a1.z = fmaf(e1, w.z, a1.z); a1.w = fmaf(e1, w.w, a1.w);
                    a2.x = fmaf(e2, w.x, a2.x); a2.y = fmaf(e2, w.y, a2.y);
                    a2.z = fmaf(e2, w.z, a2.z); a2.w = fmaf(e2, w.w, a2.w);
                    a3.x = fmaf(e3, w.x, a3.x); a3.y = fmaf(e3, w.y, a3.y);
                    a3.z = fmaf(e3, w.z, a3.z); a3.w = fmaf(e3, w.w, a3.w);
                }
            }
            *(float4*)&zpart[kk][0][cq * 4] = a0;
            *(float4*)&zpart[kk][1][cq * 4] = a1;
            *(float4*)&zpart[kk][2][cq * 4] = a2;
            *(float4*)&zpart[kk][3][cq * 4] = a3;
        }
        __syncthreads();

        // ---- reduce k-partials + x-projection -> z ----
        if (tid < BPG * CPB) {
            float s = fmaf(xsh[rb][0], wx0,
                      fmaf(xsh[rb][1], wx1,
                      fmaf(xsh[rb][2], wx2, bbv)));
            #pragma unroll
            for (int q = 0; q < KK; ++q) s += zpart[q][rb][rc];
            zsh[rb][rc] = s;
        }
        __syncthreads();

        // ---- gates + state update; publish h slice (relaxed, cache-point) ----
        if (tid < BPG * UPB) {
            const float cc = csh[gb][gu];
            const float zi = zsh[gb][gu];
            const float zf = zsh[gb][UPB   + gu];
            const float zg = zsh[gb][2*UPB + gu];
            const float zo = zsh[gb][3*UPB + gu];
            const float ig = sigmoid_(fmaf(piu, cc, zi));
            const float fg = sigmoid_(fmaf(pfu, cc, zf));
            const float gg = tanh_(zg);
            const float cn = fmaf(fg, cc, ig * gg);
            const float og = sigmoid_(fmaf(pou, cn, zo));
            const float hn = og * tanh_(cn);
            csh[gb][gu] = cn;
            if (MODE == 0) hsh[gb][unit] = hn;   // local copy for partial-y
            const int batch = gr * BPG + gb;
            __hip_atomic_store(&hbuf[(size_t)p * BATCH * UNITS + batch * UNITS + unit],
                               hn, __ATOMIC_RELAXED, __HIP_MEMORY_SCOPE_AGENT);
        }
        // __syncthreads drains vmcnt per wave -> all publishes complete at the
        // coherence point before any thread proceeds (structural ordering).
        __syncthreads();

        if (MODE == 0) {
            // ---- arrival: plain relaxed store to own padded flag line ----
            if (tid == 0)
                __hip_atomic_store(&flags[(gr * NBLK + j) * FLAG_STRIDE],
                                   (unsigned)(t + 1),
                                   __ATOMIC_RELAXED, __HIP_MEMORY_SCOPE_AGENT);

            // ---- partial y for local 25 units (parallel with poll) ----
            if (tid < BPG * 3) {
                const int pb = tid / 3, pf = tid % 3;
                float s = 0.f;
                #pragma unroll
                for (int u = 0; u < UPB; ++u)
                    s += hsh[pb][j * UPB + u] * wosh[u][pf];
                part[(((size_t)(gr * NBLK + j) * BPG + pb) * 3 + pf) * TLEN + t] = s;
            }

            // ---- all waves poll the 16 flags independently ----
            {
                const unsigned target = (unsigned)(t + 1);
                for (;;) {
                    unsigned v = target;
                    if (lane < NBLK)
                        v = __hip_atomic_load(&flags[(gr * NBLK + lane) * FLAG_STRIDE],
                                              __ATOMIC_RELAXED, __HIP_MEMORY_SCOPE_AGENT);
                    if (__ballot(v < target) == 0ull) break;
                    __builtin_amdgcn_s_sleep(1);
                }
            }

            // ---- reload full h for the group's batches ----
            if (tid < UNITS) {
                #pragma unroll
                for (int b = 0; b < BPG; ++b)
                    hsh[b][tid] = __hip_atomic_load(
                        &hbuf[(size_t)p * BATCH * UNITS + (gr * BPG + b) * UNITS + tid],
                        __ATOMIC_RELAXED, __HIP_MEMORY_SCOPE_AGENT);
            }
            __syncthreads();
        } else {
            // ---- round-4 counter barrier ----
            if (tid == 0) {
                __hip_atomic_fetch_add(myctr, 1u, __ATOMIC_RELAXED, __HIP_MEMORY_SCOPE_AGENT);
                const unsigned target = (unsigned)NBLK * (unsigned)(t + 1);
                while (__hip_atomic_load(myctr, __ATOMIC_RELAXED, __HIP_MEMORY_SCOPE_AGENT) < target) {
                    __builtin_amdgcn_s_sleep(1);
                }
            }
            __syncthreads();

            if (tid < UNITS) {
                #pragma unroll
                for (int b = 0; b < BPG; ++b)
                    hsh[b][tid] = __hip_atomic_load(
                        &hbuf[(size_t)p * BATCH * UNITS + (gr * BPG + b) * UNITS + tid],
                        __ATOMIC_RELAXED, __HIP_MEMORY_SCOPE_AGENT);
            }
            __syncthreads();

            if (j < BPG) {
                float s0 = 0.f, s1 = 0.f, s2 = 0.f;
                if (tid < UNITS) {
                    const float hv = hsh[j][tid];
                    s0 = hv * wo0; s1 = hv * wo1; s2 = hv * wo2;
                }
                #pragma unroll
                for (int off = 32; off; off >>= 1) {
                    s0 += __shfl_down(s0, off);
                    s1 += __shfl_down(s1, off);
                    s2 += __shfl_down(s2, off);
                }
                if (lane == 0) { red[wv][0] = s0; red[wv][1] = s1; red[wv][2] = s2; }
            }
            __syncthreads();
            if (j < BPG && tid < 3) {
                float r = bo;
                #pragma unroll
                for (int w2 = 0; w2 < 8; ++w2) r += red[w2][tid];
                out[((size_t)(gr * BPG + j) * TLEN + t) * 3 + tid] = r;
            }
        }
    }
}

// ---- post-kernel: out[b][t][f] = b_out[f] + sum_j part[gr][j][gb][f][t] ----
__global__ void finish_y(const float* __restrict__ part,
                         const float* __restrict__ b_out,
                         float* __restrict__ out) {
    int i = blockIdx.x * 256 + threadIdx.x;
    if (i >= BATCH * TLEN * 3) return;
    const int f = i % 3;
    const int bt = i / 3;
    const int t = bt % TLEN;
    const int b = bt / TLEN;
    const int gr = b >> 2, gb = b & 3;
    float s = b_out[f];
    #pragma unroll
    for (int j = 0; j < NBLK; ++j)
        s += part[(((size_t)(gr * NBLK + j) * BPG + gb) * 3 + f) * TLEN + t];
    out[i] = s;
}

// ---- fallback: proven round-1 single-block-per-batch kernel ----
__global__ __launch_bounds__(512) void lstm_fused_fb(
    const float* __restrict__ x, const float* __restrict__ W_x,
    const float* __restrict__ W_h, const float* __restrict__ bvec,
    const float* __restrict__ p_i, const float* __restrict__ p_f,
    const float* __restrict__ p_o, const float* __restrict__ W_out,
    const float* __restrict__ b_out, float* __restrict__ out)
{
    const int b = blockIdx.x, tid = threadIdx.x;
    const int lane = tid & 63, wv = tid >> 6;
    __shared__ float hsh[UNITS], csh[UNITS], zsh[GATES], xb[3], red[8][3];
    const float4* Wh4 = (const float4*)W_h;
    const int g = tid;
    float4 wx0, wx1, wx2, bb;
    if (g < GATES/4) {
        const float4* Wx4 = (const float4*)W_x;
        wx0 = Wx4[0*400 + g]; wx1 = Wx4[1*400 + g]; wx2 = Wx4[2*400 + g];
        bb  = ((const float4*)bvec)[g];
    }
    float piu=0.f,pfu=0.f,pou=0.f,wo0=0.f,wo1=0.f,wo2=0.f;
    if (tid < UNITS) {
        piu=p_i[tid]; pfu=p_f[tid]; pou=p_o[tid];
        wo0=W_out[tid*3]; wo1=W_out[tid*3+1]; wo2=W_out[tid*3+2];
        hsh[tid]=0.f; csh[tid]=0.f;
    }
    const float bo = (tid<3)?b_out[tid]:0.f;
    const float* xrow = x + (size_t)b*TLEN*3;
    float* orow = out + (size_t)b*TLEN*3;
    for (int t=0;t<TLEN;++t){
        if (tid<3) xb[tid]=xrow[t*3+tid];
        __syncthreads();
        const float x0=xb[0],x1=xb[1],x2=xb[2];
        if (g < GATES/4){
            float4 acc;
            acc.x=fmaf(x0,wx0.x,fmaf(x1,wx1.x,fmaf(x2,wx2.x,bb.x)));
            acc.y=fmaf(x0,wx0.y,fmaf(x1,wx1.y,fmaf(x2,wx2.y,bb.y)));
            acc.z=fmaf(x0,wx0.z,fmaf(x1,wx1.z,fmaf(x2,wx2.z,bb.z)));
            acc.w=fmaf(x0,wx0.w,fmaf(x1,wx1.w,fmaf(x2,wx2.w,bb.w)));
            const float4* wp=Wh4+g;
            #pragma unroll 8
            for(int k=0;k<UNITS;++k){
                const float hk=hsh[k]; const float4 w=wp[(size_t)k*400];
                acc.x=fmaf(hk,w.x,acc.x); acc.y=fmaf(hk,w.y,acc.y);
                acc.z=fmaf(hk,w.z,acc.z); acc.w=fmaf(hk,w.w,acc.w);
            }
            ((float4*)zsh)[g]=acc;
        }
        __syncthreads();
        float s0=0.f,s1=0.f,s2=0.f;
        if (tid<UNITS){
            const float cc=csh[tid];
            const float zi=zsh[tid],zf=zsh[tid+UNITS],zg=zsh[tid+2*UNITS],zo=zsh[tid+3*UNITS];
            const float ig=sigmoid_(fmaf(piu,cc,zi));
            const float fg=sigmoid_(fmaf(pfu,cc,zf));
            const float gg=tanh_(zg);
            const float cn=fmaf(fg,cc,ig*gg);
            const float og=sigmoid_(fmaf(pou,cn,zo));
            const float hn=og*tanh_(cn);
            csh[tid]=cn; hsh[tid]=hn;
            s0=hn*wo0; s1=hn*wo1; s2=hn*wo2;
        }
        #pragma unroll
        for(int off=32;off;off>>=1){
            s0+=__shfl_down(s0,off); s1+=__shfl_down(s1,off); s2+=__shfl_down(s2,off);
        }
        if(lane==0){red[wv][0]=s0;red[wv][1]=s1;red[wv][2]=s2;}
        __syncthreads();
        if(tid<3){
            float r=bo;
            #pragma unroll
            for(int w2=0;w2<8;++w2) r+=red[w2][tid];
            orow[t*3+tid]=r;
        }
    }
}

extern "C" void kernel_launch(void* const* d_in, const int* in_sizes, int n_in,
                              void* d_out, int out_size, void* d_ws, size_t ws_size,
                              hipStream_t stream) {
    const float* x     = (const float*)d_in[0];
    const float* W_x   = (const float*)d_in[1];
    const float* W_h   = (const float*)d_in[2];
    const float* b     = (const float*)d_in[3];
    const float* p_i   = (const float*)d_in[4];
    const float* p_f   = (const float*)d_in[5];
    const float* p_o   = (const float*)d_in[6];
    const float* W_out = (const float*)d_in[7];
    const float* b_out = (const float*)d_in[8];
    float* out = (float*)d_out;

    if (ws_size < WS_R4) {
        lstm_fused_fb<<<BATCH, 512, 0, stream>>>(x, W_x, W_h, b, p_i, p_f, p_o,
                                                 W_out, b_out, out);
        return;
    }

    uint8_t* ws = (uint8_t*)d_ws;
    float* wbuf = (float*)(ws + WBUF_OFF);
    float* hbuf = (float*)(ws + HBUF_OFF);
    unsigned int* ctr   = (unsigned int*)(ws + CTR_OFF);
    unsigned int* flags = (unsigned int*)(ws + FLAGS_OFF);
    float* part = (float*)(ws + PART_OFF);

    reorder_w<<<(NBLK * UNITS * CPB + 255) / 256, 256, 0, stream>>>(W_h, wbuf);

    if (ws_size >= WS_FULL) {
        hipMemsetAsync(flags, 0, FLAGS_SZ, stream);
        lstm_mb<0><<<NGRP * NBLK, 512, 0, stream>>>(x, W_x, b, p_i, p_f, p_o,
                                                    W_out, b_out, wbuf, hbuf,
                                                    ctr, flags, part, out);
        finish_y<<<(BATCH * TLEN * 3 + 255) / 256, 256, 0, stream>>>(part, b_out, out);
    } else {
        hipMemsetAsync(ctr, 0, CTR_SZ, stream);
        lstm_mb<1><<<NGRP * NBLK, 512, 0, stream>>>(x, W_x, b, p_i, p_f, p_o,
                                                    W_out, b_out, wbuf, hbuf,
                                                    ctr, flags, part, out);
    }
}

// Round 6
// 3082.896 us; speedup vs baseline: 6.6221x; 1.1565x over previous
//
#include <hip/hip_runtime.h>
#include <hip/hip_bf16.h>
#include <stdint.h>

#define UNITS 400
#define GATES 1600
#define TLEN  1000
#define BATCH 64

#define NBLK 16        // blocks per group (weight slices)
#define NGRP 16        // groups
#define BPG  4         // batches per group
#define UPB  25        // units per block
#define CPB  100       // cols per block = UPB*4 gates
#define KK   20        // k-split factor (threads 0..499 are z-role)
#define KCH  20        // k-chunk = UNITS/KK -> 20 float4 weight regs/thread
#define FLAG_STRIDE 32

// d_ws layout
#define WBUF_OFF  0
#define WBUF_SZ   (NBLK*UNITS*CPB*4)                 // 2,560,000
#define HBUF_OFF  (WBUF_OFF + WBUF_SZ)
#define HBUF_SZ   (2*BATCH*UNITS*8)                  //   409,600 (u64 packets)
#define CTR_OFF   (HBUF_OFF + HBUF_SZ)
#define CTR_SZ    (NGRP*FLAG_STRIDE*4)               //     2,048
#define PART_OFF  (CTR_OFF + CTR_SZ)
#define PART_SZ   (NGRP*NBLK*BPG*3*TLEN*4)           // 12,288,000
#define WS_R4     ((size_t)PART_OFF)                 // counter-mode needs
#define WS_FULL   ((size_t)PART_OFF + PART_SZ)       // full-mode needs

__device__ __forceinline__ float sigmoid_(float x) {
    return 1.0f / (1.0f + __expf(-x));
}
__device__ __forceinline__ float tanh_(float x) {
    return 1.0f - 2.0f / (__expf(2.0f * x) + 1.0f);
}

// ---- one-time weight reorder: wbuf[j][k][c] = W_h[k][(c/25)*400 + j*25 + c%25] ----
__global__ void reorder_w(const float* __restrict__ W_h, float* __restrict__ wbuf) {
    int i = blockIdx.x * 256 + threadIdx.x;
    if (i >= NBLK * UNITS * CPB) return;
    int c = i % CPB;
    int k = (i / CPB) % UNITS;
    int j = i / (CPB * UNITS);
    int g = c / UPB, u2 = c % UPB;
    int col = g * UNITS + j * UPB + u2;
    wbuf[i] = W_h[k * GATES + col];
}

// MODE 0: tag-in-data u64 exchange + deferred y. MODE 1: round-4 counter protocol (f32 hbuf).
template<int MODE>
__global__ __launch_bounds__(512, 1) void lstm_mb(
    const float* __restrict__ x,
    const float* __restrict__ W_x,
    const float* __restrict__ bvec,
    const float* __restrict__ p_i,
    const float* __restrict__ p_f,
    const float* __restrict__ p_o,
    const float* __restrict__ W_out,
    const float* __restrict__ b_out,
    const float* __restrict__ wbuf,
    unsigned long long* __restrict__ hbuf64,  // [2][B][U] {tag,val} (MODE 0)
    float*       __restrict__ hbuf32,         // same region as f32 (MODE 1)
    unsigned int* __restrict__ ctr,           // [NGRP] (MODE 1)
    float*       __restrict__ part,           // [NGRP*NBLK][BPG][3][TLEN] (MODE 0)
    float*       __restrict__ out)
{
    const int gr  = blockIdx.x % NGRP;   // XCD-local heuristic (perf only)
    const int j   = blockIdx.x / NGRP;
    const int tid = threadIdx.x;
    const int lane = tid & 63;
    const int wv   = tid >> 6;

    __shared__ float hsh[BPG][UNITS];
    __shared__ float zpart[KK][BPG][CPB];
    __shared__ float zsh[BPG][CPB];
    __shared__ float csh[BPG][UPB];
    __shared__ float xsh[BPG][4];
    __shared__ float red[8][4];
    __shared__ float wosh[UPB][3];

    const float* wslice = wbuf + (size_t)j * UNITS * CPB;

    // ---- roles ----
    const int kk = tid / 25, cq = tid % 25;       // z-role: tid < 500
    const bool zrole = (tid < KK * 25);
    const int k0 = kk * KCH;
    const int rb = tid / CPB, rc = tid % CPB;     // reduce-role: tid < 400
    const int gb = tid / UPB, gu = tid % UPB;     // gate-role: tid < 100

    // ---- register-resident weight patch ----
    float4 wreg[KCH];
    if (zrole) {
        #pragma unroll
        for (int r = 0; r < KCH; ++r)
            wreg[r] = *(const float4*)&wslice[(size_t)(k0 + r) * CPB + cq * 4];
    }

    // ---- t-invariant hoists ----
    float wx0 = 0.f, wx1 = 0.f, wx2 = 0.f, bbv = 0.f;
    if (tid < BPG * CPB) {
        int gcol = (rc / UPB) * UNITS + j * UPB + (rc % UPB);
        wx0 = W_x[0 * GATES + gcol];
        wx1 = W_x[1 * GATES + gcol];
        wx2 = W_x[2 * GATES + gcol];
        bbv = bvec[gcol];
    }
    float piu = 0.f, pfu = 0.f, pou = 0.f;
    int unit = 0;
    if (tid < BPG * UPB) {
        unit = j * UPB + gu;
        piu = p_i[unit]; pfu = p_f[unit]; pou = p_o[unit];
    }
    float wo0 = 0.f, wo1 = 0.f, wo2 = 0.f;
    if (MODE == 1 && tid < UNITS) {
        wo0 = W_out[tid * 3 + 0];
        wo1 = W_out[tid * 3 + 1];
        wo2 = W_out[tid * 3 + 2];
    }
    const float bo = (tid < 3) ? b_out[tid] : 0.f;
    if (MODE == 0 && tid < UPB * 3) {
        wosh[tid / 3][tid % 3] = W_out[(j * UPB + tid / 3) * 3 + (tid % 3)];
    }

    // ---- state init ----
    if (tid < UNITS) {
        #pragma unroll
        for (int b = 0; b < BPG; ++b) hsh[b][tid] = 0.f;
    }
    if (tid < BPG * UPB) csh[gb][gu] = 0.f;
    __syncthreads();

    unsigned int* myctr = ctr + gr * FLAG_STRIDE;

    for (int t = 0; t < TLEN; ++t) {
        const int p = t & 1;

        // ---- stage x_t ----
        if (tid < BPG * 3) {
            int b = tid / 3, f = tid % 3;
            xsh[b][f] = x[((size_t)(gr * BPG + b) * TLEN + t) * 3 + f];
        }

        // ---- z-loop: h @ W_h partials from register weights ----
        if (zrole) {
            float4 a0 = {0,0,0,0}, a1 = a0, a2 = a0, a3 = a0;
            #pragma unroll
            for (int ro = 0; ro < KCH; ro += 4) {
                const float4 h0 = *(const float4*)&hsh[0][k0 + ro];
                const float4 h1 = *(const float4*)&hsh[1][k0 + ro];
                const float4 h2 = *(const float4*)&hsh[2][k0 + ro];
                const float4 h3 = *(const float4*)&hsh[3][k0 + ro];
                #pragma unroll
                for (int dr = 0; dr < 4; ++dr) {
                    const float4 w = wreg[ro + dr];
                    const float e0 = (dr==0)?h0.x:(dr==1)?h0.y:(dr==2)?h0.z:h0.w;
                    const float e1 = (dr==0)?h1.x:(dr==1)?h1.y:(dr==2)?h1.z:h1.w;
                    const float e2 = (dr==0)?h2.x:(dr==1)?h2.y:(dr==2)?h2.z:h2.w;
                    const float e3 = (dr==0)?h3.x:(dr==1)?h3.y:(dr==2)?h3.z:h3.w;
                    a0.x = fmaf(e0, w.x, a0.x); a0.y = fmaf(e0, w.y, a0.y);
                    a0.z = fmaf(e0, w.z, a0.z); a0.w = fmaf(e0, w.w, a0.w);
                    a1.x = fmaf(e1, w.x, a1.x); a1.y = fmaf(e1, w.y, a1.y);
                    a1.z = fmaf(e1, w.z, a1.z); a1.w = fmaf(e1, w.w, a1.w);
                    a2.x = fmaf(e2, w.x, a2.x); a2.y = fmaf(e2, w.y, a2.y);
                    a2.z = fmaf(e2, w.z, a2.z); a2.w = fmaf(e2, w.w, a2.w);
                    a3.x = fmaf(e3, w.x, a3.x); a3.y = fmaf(e3, w.y, a3.y);
                    a3.z = fmaf(e3, w.z, a3.z); a3.w = fmaf(e3, w.w, a3.w);
                }
            }
            *(float4*)&zpart[kk][0][cq * 4] = a0;
            *(float4*)&zpart[kk][1][cq * 4] = a1;
            *(float4*)&zpart[kk][2][cq * 4] = a2;
            *(float4*)&zpart[kk][3][cq * 4] = a3;
        }
        __syncthreads();

        // ---- reduce k-partials + x-projection -> z ----
        if (tid < BPG * CPB) {
            float s = fmaf(xsh[rb][0], wx0,
                      fmaf(xsh[rb][1], wx1,
                      fmaf(xsh[rb][2], wx2, bbv)));
            #pragma unroll
            for (int q = 0; q < KK; ++q) s += zpart[q][rb][rc];
            zsh[rb][rc] = s;
        }
        __syncthreads();

        // ---- gates + state update; publish {h, tag} packet (single 8B atomic) ----
        if (tid < BPG * UPB) {
            const float cc = csh[gb][gu];
            const float zi = zsh[gb][gu];
            const float zf = zsh[gb][UPB   + gu];
            const float zg = zsh[gb][2*UPB + gu];
            const float zo = zsh[gb][3*UPB + gu];
            const float ig = sigmoid_(fmaf(piu, cc, zi));
            const float fg = sigmoid_(fmaf(pfu, cc, zf));
            const float gg = tanh_(zg);
            const float cn = fmaf(fg, cc, ig * gg);
            const float og = sigmoid_(fmaf(pou, cn, zo));
            const float hn = og * tanh_(cn);
            csh[gb][gu] = cn;
            const int batch = gr * BPG + gb;
            if (MODE == 0) {
                hsh[gb][unit] = hn;   // fresh local copy for partial-y
                const unsigned long long pkt =
                    ((unsigned long long)(unsigned)(t + 1) << 32) |
                    (unsigned long long)__float_as_uint(hn);
                __hip_atomic_store(&hbuf64[(size_t)p * BATCH * UNITS + batch * UNITS + unit],
                                   pkt, __ATOMIC_RELAXED, __HIP_MEMORY_SCOPE_AGENT);
            } else {
                __hip_atomic_store(&hbuf32[(size_t)p * BATCH * UNITS + batch * UNITS + unit],
                                   hn, __ATOMIC_RELAXED, __HIP_MEMORY_SCOPE_AGENT);
            }
        }
        __syncthreads();   // hsh(own slice)/csh settled; (MODE1: publishes drained)

        if (MODE == 0) {
            // ---- partial y for local 25 units (off critical path) ----
            if (tid < BPG * 3) {
                const int pb = tid / 3, pf = tid % 3;
                float s = 0.f;
                #pragma unroll
                for (int u = 0; u < UPB; ++u)
                    s += hsh[pb][j * UPB + u] * wosh[u][pf];
                part[(((size_t)(gr * NBLK + j) * BPG + pb) * 3 + pf) * TLEN + t] = s;
            }

            // ---- reload h: poll tag-in-data packets directly (no flags) ----
            if (tid < UNITS) {
                const unsigned want = (unsigned)(t + 1);
                const size_t base = (size_t)p * BATCH * UNITS
                                  + (size_t)gr * BPG * UNITS + tid;
                unsigned long long v0, v1, v2, v3;
                for (;;) {
                    v0 = __hip_atomic_load(&hbuf64[base + 0 * UNITS],
                                           __ATOMIC_RELAXED, __HIP_MEMORY_SCOPE_AGENT);
                    v1 = __hip_atomic_load(&hbuf64[base + 1 * UNITS],
                                           __ATOMIC_RELAXED, __HIP_MEMORY_SCOPE_AGENT);
                    v2 = __hip_atomic_load(&hbuf64[base + 2 * UNITS],
                                           __ATOMIC_RELAXED, __HIP_MEMORY_SCOPE_AGENT);
                    v3 = __hip_atomic_load(&hbuf64[base + 3 * UNITS],
                                           __ATOMIC_RELAXED, __HIP_MEMORY_SCOPE_AGENT);
                    if ((unsigned)(v0 >> 32) == want && (unsigned)(v1 >> 32) == want &&
                        (unsigned)(v2 >> 32) == want && (unsigned)(v3 >> 32) == want)
                        break;
                    __builtin_amdgcn_s_sleep(1);
                }
                hsh[0][tid] = __uint_as_float((unsigned)v0);
                hsh[1][tid] = __uint_as_float((unsigned)v1);
                hsh[2][tid] = __uint_as_float((unsigned)v2);
                hsh[3][tid] = __uint_as_float((unsigned)v3);
            }
            __syncthreads();
        } else {
            // ---- round-4 counter barrier ----
            if (tid == 0) {
                __hip_atomic_fetch_add(myctr, 1u, __ATOMIC_RELAXED, __HIP_MEMORY_SCOPE_AGENT);
                const unsigned target = (unsigned)NBLK * (unsigned)(t + 1);
                while (__hip_atomic_load(myctr, __ATOMIC_RELAXED, __HIP_MEMORY_SCOPE_AGENT) < target) {
                    __builtin_amdgcn_s_sleep(1);
                }
            }
            __syncthreads();

            if (tid < UNITS) {
                #pragma unroll
                for (int b = 0; b < BPG; ++b)
                    hsh[b][tid] = __hip_atomic_load(
                        &hbuf32[(size_t)p * BATCH * UNITS + (gr * BPG + b) * UNITS + tid],
                        __ATOMIC_RELAXED, __HIP_MEMORY_SCOPE_AGENT);
            }
            __syncthreads();

            if (j < BPG) {
                float s0 = 0.f, s1 = 0.f, s2 = 0.f;
                if (tid < UNITS) {
                    const float hv = hsh[j][tid];
                    s0 = hv * wo0; s1 = hv * wo1; s2 = hv * wo2;
                }
                #pragma unroll
                for (int off = 32; off; off >>= 1) {
                    s0 += __shfl_down(s0, off);
                    s1 += __shfl_down(s1, off);
                    s2 += __shfl_down(s2, off);
                }
                if (lane == 0) { red[wv][0] = s0; red[wv][1] = s1; red[wv][2] = s2; }
            }
            __syncthreads();
            if (j < BPG && tid < 3) {
                float r = bo;
                #pragma unroll
                for (int w2 = 0; w2 < 8; ++w2) r += red[w2][tid];
                out[((size_t)(gr * BPG + j) * TLEN + t) * 3 + tid] = r;
            }
        }
    }
}

// ---- post-kernel: out[b][t][f] = b_out[f] + sum_j part[gr][j][gb][f][t] ----
__global__ void finish_y(const float* __restrict__ part,
                         const float* __restrict__ b_out,
                         float* __restrict__ out) {
    int i = blockIdx.x * 256 + threadIdx.x;
    if (i >= BATCH * TLEN * 3) return;
    const int f = i % 3;
    const int bt = i / 3;
    const int t = bt % TLEN;
    const int b = bt / TLEN;
    const int gr = b >> 2, gb = b & 3;
    float s = b_out[f];
    #pragma unroll
    for (int j = 0; j < NBLK; ++j)
        s += part[(((size_t)(gr * NBLK + j) * BPG + gb) * 3 + f) * TLEN + t];
    out[i] = s;
}

// ---- fallback: proven round-1 single-block-per-batch kernel ----
__global__ __launch_bounds__(512) void lstm_fused_fb(
    const float* __restrict__ x, const float* __restrict__ W_x,
    const float* __restrict__ W_h, const float* __restrict__ bvec,
    const float* __restrict__ p_i, const float* __restrict__ p_f,
    const float* __restrict__ p_o, const float* __restrict__ W_out,
    const float* __restrict__ b_out, float* __restrict__ out)
{
    const int b = blockIdx.x, tid = threadIdx.x;
    const int lane = tid & 63, wv = tid >> 6;
    __shared__ float hsh[UNITS], csh[UNITS], zsh[GATES], xb[3], red[8][3];
    const float4* Wh4 = (const float4*)W_h;
    const int g = tid;
    float4 wx0, wx1, wx2, bb;
    if (g < GATES/4) {
        const float4* Wx4 = (const float4*)W_x;
        wx0 = Wx4[0*400 + g]; wx1 = Wx4[1*400 + g]; wx2 = Wx4[2*400 + g];
        bb  = ((const float4*)bvec)[g];
    }
    float piu=0.f,pfu=0.f,pou=0.f,wo0=0.f,wo1=0.f,wo2=0.f;
    if (tid < UNITS) {
        piu=p_i[tid]; pfu=p_f[tid]; pou=p_o[tid];
        wo0=W_out[tid*3]; wo1=W_out[tid*3+1]; wo2=W_out[tid*3+2];
        hsh[tid]=0.f; csh[tid]=0.f;
    }
    const float bo = (tid<3)?b_out[tid]:0.f;
    const float* xrow = x + (size_t)b*TLEN*3;
    float* orow = out + (size_t)b*TLEN*3;
    for (int t=0;t<TLEN;++t){
        if (tid<3) xb[tid]=xrow[t*3+tid];
        __syncthreads();
        const float x0=xb[0],x1=xb[1],x2=xb[2];
        if (g < GATES/4){
            float4 acc;
            acc.x=fmaf(x0,wx0.x,fmaf(x1,wx1.x,fmaf(x2,wx2.x,bb.x)));
            acc.y=fmaf(x0,wx0.y,fmaf(x1,wx1.y,fmaf(x2,wx2.y,bb.y)));
            acc.z=fmaf(x0,wx0.z,fmaf(x1,wx1.z,fmaf(x2,wx2.z,bb.z)));
            acc.w=fmaf(x0,wx0.w,fmaf(x1,wx1.w,fmaf(x2,wx2.w,bb.w)));
            const float4* wp=Wh4+g;
            #pragma unroll 8
            for(int k=0;k<UNITS;++k){
                const float hk=hsh[k]; const float4 w=wp[(size_t)k*400];
                acc.x=fmaf(hk,w.x,acc.x); acc.y=fmaf(hk,w.y,acc.y);
                acc.z=fmaf(hk,w.z,acc.z); acc.w=fmaf(hk,w.w,acc.w);
            }
            ((float4*)zsh)[g]=acc;
        }
        __syncthreads();
        float s0=0.f,s1=0.f,s2=0.f;
        if (tid<UNITS){
            const float cc=csh[tid];
            const float zi=zsh[tid],zf=zsh[tid+UNITS],zg=zsh[tid+2*UNITS],zo=zsh[tid+3*UNITS];
            const float ig=sigmoid_(fmaf(piu,cc,zi));
            const float fg=sigmoid_(fmaf(pfu,cc,zf));
            const float gg=tanh_(zg);
            const float cn=fmaf(fg,cc,ig*gg);
            const float og=sigmoid_(fmaf(pou,cn,zo));
            const float hn=og*tanh_(cn);
            csh[tid]=cn; hsh[tid]=hn;
            s0=hn*wo0; s1=hn*wo1; s2=hn*wo2;
        }
        #pragma unroll
        for(int off=32;off;off>>=1){
            s0+=__shfl_down(s0,off); s1+=__shfl_down(s1,off); s2+=__shfl_down(s2,off);
        }
        if(lane==0){red[wv][0]=s0;red[wv][1]=s1;red[wv][2]=s2;}
        __syncthreads();
        if(tid<3){
            float r=bo;
            #pragma unroll
            for(int w2=0;w2<8;++w2) r+=red[w2][tid];
            orow[t*3+tid]=r;
        }
    }
}

extern "C" void kernel_launch(void* const* d_in, const int* in_sizes, int n_in,
                              void* d_out, int out_size, void* d_ws, size_t ws_size,
                              hipStream_t stream) {
    const float* x     = (const float*)d_in[0];
    const float* W_x   = (const float*)d_in[1];
    const float* W_h   = (const float*)d_in[2];
    const float* b     = (const float*)d_in[3];
    const float* p_i   = (const float*)d_in[4];
    const float* p_f   = (const float*)d_in[5];
    const float* p_o   = (const float*)d_in[6];
    const float* W_out = (const float*)d_in[7];
    const float* b_out = (const float*)d_in[8];
    float* out = (float*)d_out;

    if (ws_size < WS_R4) {
        lstm_fused_fb<<<BATCH, 512, 0, stream>>>(x, W_x, W_h, b, p_i, p_f, p_o,
                                                 W_out, b_out, out);
        return;
    }

    uint8_t* ws = (uint8_t*)d_ws;
    float* wbuf = (float*)(ws + WBUF_OFF);
    unsigned long long* hbuf64 = (unsigned long long*)(ws + HBUF_OFF);
    float* hbuf32 = (float*)(ws + HBUF_OFF);
    unsigned int* ctr = (unsigned int*)(ws + CTR_OFF);
    float* part = (float*)(ws + PART_OFF);

    reorder_w<<<(NBLK * UNITS * CPB + 255) / 256, 256, 0, stream>>>(W_h, wbuf);

    if (ws_size >= WS_FULL) {
        hipMemsetAsync(hbuf64, 0, HBUF_SZ, stream);   // kill stale tags (graph replay)
        lstm_mb<0><<<NGRP * NBLK, 512, 0, stream>>>(x, W_x, b, p_i, p_f, p_o,
                                                    W_out, b_out, wbuf,
                                                    hbuf64, hbuf32, ctr, part, out);
        finish_y<<<(BATCH * TLEN * 3 + 255) / 256, 256, 0, stream>>>(part, b_out, out);
    } else {
        hipMemsetAsync(ctr, 0, CTR_SZ, stream);
        lstm_mb<1><<<NGRP * NBLK, 512, 0, stream>>>(x, W_x, b, p_i, p_f, p_o,
                                                    W_out, b_out, wbuf,
                                                    hbuf64, hbuf32, ctr, part, out);
    }
}

// Round 7
// 3032.286 us; speedup vs baseline: 6.7326x; 1.0167x over previous
//
#include <hip/hip_runtime.h>
#include <hip/hip_bf16.h>
#include <stdint.h>

#define UNITS 400
#define GATES 1600
#define TLEN  1000
#define BATCH 64

#define NBLK 8         // blocks per group (weight slices)
#define NGRP 32        // groups (8 blocks of a group share an XCD under round-robin)
#define BPG  2         // batches per group
#define UPB  50        // units per block
#define CPB  200       // cols per block
#define KK   10        // k-split
#define KCH  40        // k-chunk -> 40 float4 weight regs/thread

// d_ws layout
#define WBUF_OFF  0
#define WBUF_SZ   (NBLK*UNITS*CPB*4)                 // 2,560,000
#define HBUF_OFF  (WBUF_OFF + WBUF_SZ)
#define HBUF_SZ   (2*BATCH*UNITS*8)                  //   409,600 (u64 packets)
#define PART_OFF  (HBUF_OFF + HBUF_SZ)
#define PART_SZ   (NGRP*NBLK*BPG*3*TLEN*4)           // 6,144,000
#define WS_FULL   ((size_t)PART_OFF + PART_SZ)

__device__ __forceinline__ float sigmoid_(float x) {
    return 1.0f / (1.0f + __expf(-x));
}
__device__ __forceinline__ float tanh_(float x) {
    return 1.0f - 2.0f / (__expf(2.0f * x) + 1.0f);
}

// ---- one-time weight reorder: wbuf[j][k][c] = W_h[k][(c/UPB)*UNITS + j*UPB + c%UPB] ----
__global__ void reorder_w(const float* __restrict__ W_h, float* __restrict__ wbuf) {
    int i = blockIdx.x * 256 + threadIdx.x;
    if (i >= NBLK * UNITS * CPB) return;
    int c = i % CPB;
    int k = (i / CPB) % UNITS;
    int j = i / (CPB * UNITS);
    int g = c / UPB, u2 = c % UPB;
    int col = g * UNITS + j * UPB + u2;
    wbuf[i] = W_h[k * GATES + col];
}

// ---- main: register weights, fused gates, tag-in-data exchange, 2 syncs/step ----
__global__ __launch_bounds__(512, 1) void lstm_mb(
    const float* __restrict__ x,      // [B,T,3]
    const float* __restrict__ W_x,    // [3,1600]
    const float* __restrict__ bvec,   // [1600]
    const float* __restrict__ p_i,
    const float* __restrict__ p_f,
    const float* __restrict__ p_o,
    const float* __restrict__ W_out,  // [400,3]
    const float* __restrict__ wbuf,
    unsigned long long* __restrict__ hbuf,   // [2][B][U] {tag,val}
    float*       __restrict__ part,          // [NGRP*NBLK][BPG][3][TLEN]
    float*       __restrict__ out)           // unused here (finish_y writes out)
{
    const int gr  = blockIdx.x % NGRP;   // XCD-local heuristic (perf only)
    const int j   = blockIdx.x / NGRP;
    const int tid = threadIdx.x;

    __shared__ float hsh[BPG][UNITS];          // 3.2 KB
    __shared__ float zpart[KK][BPG][CPB];      // 16 KB
    __shared__ float wosh[UPB][3];

    const float* wslice = wbuf + (size_t)j * UNITS * CPB;

    // ---- roles ----
    const int kk = tid / 50, cq = tid % 50;       // z-role: tid < 500
    const bool zrole = (tid < KK * 50);
    const int k0 = kk * KCH;

    const int gb = tid / UPB, gu = tid % UPB;     // gate-role: tid < 100
    const bool grole = (tid < BPG * UPB);

    const bool prole = (tid < UNITS) && (tid / UPB != j);  // poll-role: skip own slice
    const bool yrole = (tid >= 500) && (tid < 500 + BPG * 3);
    const int yb = (tid - 500) / 3, yf = (tid - 500) % 3;

    // ---- register-resident weight patch: 40 x float4 (static indexing) ----
    float4 wreg[KCH];
    if (zrole) {
        #pragma unroll
        for (int r = 0; r < KCH; ++r)
            wreg[r] = *(const float4*)&wslice[(size_t)(k0 + r) * CPB + cq * 4];
    }

    // ---- gate-thread hoists ----
    int unit = 0, batch = 0;
    float wxr[3][4], bb[4];
    float piu = 0.f, pfu = 0.f, pou = 0.f, cc = 0.f;
    if (grole) {
        unit  = j * UPB + gu;
        batch = gr * BPG + gb;
        #pragma unroll
        for (int g = 0; g < 4; ++g) {
            const int gcol = g * UNITS + unit;
            wxr[0][g] = W_x[0 * GATES + gcol];
            wxr[1][g] = W_x[1 * GATES + gcol];
            wxr[2][g] = W_x[2 * GATES + gcol];
            bb[g]     = bvec[gcol];
        }
        piu = p_i[unit]; pfu = p_f[unit]; pou = p_o[unit];
    }
    if (tid < UPB * 3) wosh[tid / 3][tid % 3] = W_out[(j * UPB + tid / 3) * 3 + (tid % 3)];

    // ---- state init ----
    if (tid < UNITS) { hsh[0][tid] = 0.f; hsh[1][tid] = 0.f; }
    __syncthreads();

    for (int t = 0; t < TLEN; ++t) {
        const int p = t & 1;

        // ================= A: z-partials (+ deferred partial-y for t-1) =========
        if (zrole) {
            float4 a0 = {0,0,0,0}, a1 = a0;
            #pragma unroll
            for (int ro = 0; ro < KCH; ro += 4) {
                const float4 h0 = *(const float4*)&hsh[0][k0 + ro];
                const float4 h1 = *(const float4*)&hsh[1][k0 + ro];
                #pragma unroll
                for (int dr = 0; dr < 4; ++dr) {
                    const float4 w = wreg[ro + dr];
                    const float e0 = (dr==0)?h0.x:(dr==1)?h0.y:(dr==2)?h0.z:h0.w;
                    const float e1 = (dr==0)?h1.x:(dr==1)?h1.y:(dr==2)?h1.z:h1.w;
                    a0.x = fmaf(e0, w.x, a0.x); a0.y = fmaf(e0, w.y, a0.y);
                    a0.z = fmaf(e0, w.z, a0.z); a0.w = fmaf(e0, w.w, a0.w);
                    a1.x = fmaf(e1, w.x, a1.x); a1.y = fmaf(e1, w.y, a1.y);
                    a1.z = fmaf(e1, w.z, a1.z); a1.w = fmaf(e1, w.w, a1.w);
                }
            }
            *(float4*)&zpart[kk][0][cq * 4] = a0;
            *(float4*)&zpart[kk][1][cq * 4] = a1;
        } else if (yrole && t > 0) {
            // y partial for step t-1: hsh currently holds h_{t} = output h of step t-1
            float s = 0.f;
            #pragma unroll
            for (int u = 0; u < UPB; ++u)
                s += hsh[yb][j * UPB + u] * wosh[u][yf];
            part[(((size_t)(gr * NBLK + j) * BPG + yb) * 3 + yf) * TLEN + (t - 1)] = s;
        }
        __syncthreads();   // zpart ready; hsh reads done

        // ================= B: fused reduce + gates + publish (tid<100) ==========
        if (grole) {
            const float x0 = x[((size_t)batch * TLEN + t) * 3 + 0];
            const float x1 = x[((size_t)batch * TLEN + t) * 3 + 1];
            const float x2 = x[((size_t)batch * TLEN + t) * 3 + 2];
            float s[4];
            #pragma unroll
            for (int g = 0; g < 4; ++g) {
                float acc = fmaf(x0, wxr[0][g],
                            fmaf(x1, wxr[1][g],
                            fmaf(x2, wxr[2][g], bb[g])));
                #pragma unroll
                for (int q = 0; q < KK; ++q) acc += zpart[q][gb][g * UPB + gu];
                s[g] = acc;
            }
            const float ig = sigmoid_(fmaf(piu, cc, s[0]));
            const float fg = sigmoid_(fmaf(pfu, cc, s[1]));
            const float gg = tanh_(s[2]);
            const float cn = fmaf(fg, cc, ig * gg);
            const float og = sigmoid_(fmaf(pou, cn, s[3]));
            const float hn = og * tanh_(cn);
            cc = cn;
            hsh[gb][unit] = hn;    // own slice locally
            const unsigned long long pkt =
                ((unsigned long long)(unsigned)(t + 1) << 32) |
                (unsigned long long)__float_as_uint(hn);
            __hip_atomic_store(&hbuf[(size_t)p * BATCH * UNITS + (size_t)batch * UNITS + unit],
                               pkt, __ATOMIC_RELAXED, __HIP_MEMORY_SCOPE_AGENT);
        }

        // ================= C: poll remote slices (overlaps B of other threads) ==
        if (prole) {
            const unsigned want = (unsigned)(t + 1);
            const size_t base = (size_t)p * BATCH * UNITS
                              + (size_t)(gr * BPG) * UNITS + tid;
            unsigned long long v0, v1;
            for (;;) {
                v0 = __hip_atomic_load(&hbuf[base],
                                       __ATOMIC_RELAXED, __HIP_MEMORY_SCOPE_AGENT);
                v1 = __hip_atomic_load(&hbuf[base + UNITS],
                                       __ATOMIC_RELAXED, __HIP_MEMORY_SCOPE_AGENT);
                if ((unsigned)(v0 >> 32) == want && (unsigned)(v1 >> 32) == want) break;
                __builtin_amdgcn_s_sleep(2);
            }
            hsh[0][tid] = __uint_as_float((unsigned)v0);
            hsh[1][tid] = __uint_as_float((unsigned)v1);
        }
        __syncthreads();   // hsh = h_{t+1} complete
    }

    // ---- epilogue: y partial for final step ----
    if (yrole) {
        float s = 0.f;
        #pragma unroll
        for (int u = 0; u < UPB; ++u)
            s += hsh[yb][j * UPB + u] * wosh[u][yf];
        part[(((size_t)(gr * NBLK + j) * BPG + yb) * 3 + yf) * TLEN + (TLEN - 1)] = s;
    }
}

// ---- post-kernel: out[b][t][f] = b_out[f] + sum_j part[gr][j][gb][f][t] ----
__global__ void finish_y(const float* __restrict__ part,
                         const float* __restrict__ b_out,
                         float* __restrict__ out) {
    int i = blockIdx.x * 256 + threadIdx.x;
    if (i >= BATCH * TLEN * 3) return;
    const int f = i % 3;
    const int bt = i / 3;
    const int t = bt % TLEN;
    const int b = bt / TLEN;
    const int gr = b / BPG, gb = b % BPG;
    float s = b_out[f];
    #pragma unroll
    for (int j = 0; j < NBLK; ++j)
        s += part[(((size_t)(gr * NBLK + j) * BPG + gb) * 3 + f) * TLEN + t];
    out[i] = s;
}

// ---- fallback: proven round-1 single-block-per-batch kernel ----
__global__ __launch_bounds__(512) void lstm_fused_fb(
    const float* __restrict__ x, const float* __restrict__ W_x,
    const float* __restrict__ W_h, const float* __restrict__ bvec,
    const float* __restrict__ p_i, const float* __restrict__ p_f,
    const float* __restrict__ p_o, const float* __restrict__ W_out,
    const float* __restrict__ b_out, float* __restrict__ out)
{
    const int b = blockIdx.x, tid = threadIdx.x;
    const int lane = tid & 63, wv = tid >> 6;
    __shared__ float hsh[UNITS], csh[UNITS], zsh[GATES], xb[3], red[8][3];
    const float4* Wh4 = (const float4*)W_h;
    const int g = tid;
    float4 wx0, wx1, wx2, bb;
    if (g < GATES/4) {
        const float4* Wx4 = (const float4*)W_x;
        wx0 = Wx4[0*400 + g]; wx1 = Wx4[1*400 + g]; wx2 = Wx4[2*400 + g];
        bb  = ((const float4*)bvec)[g];
    }
    float piu=0.f,pfu=0.f,pou=0.f,wo0=0.f,wo1=0.f,wo2=0.f;
    if (tid < UNITS) {
        piu=p_i[tid]; pfu=p_f[tid]; pou=p_o[tid];
        wo0=W_out[tid*3]; wo1=W_out[tid*3+1]; wo2=W_out[tid*3+2];
        hsh[tid]=0.f; csh[tid]=0.f;
    }
    const float bo = (tid<3)?b_out[tid]:0.f;
    const float* xrow = x + (size_t)b*TLEN*3;
    float* orow = out + (size_t)b*TLEN*3;
    for (int t=0;t<TLEN;++t){
        if (tid<3) xb[tid]=xrow[t*3+tid];
        __syncthreads();
        const float x0=xb[0],x1=xb[1],x2=xb[2];
        if (g < GATES/4){
            float4 acc;
            acc.x=fmaf(x0,wx0.x,fmaf(x1,wx1.x,fmaf(x2,wx2.x,bb.x)));
            acc.y=fmaf(x0,wx0.y,fmaf(x1,wx1.y,fmaf(x2,wx2.y,bb.y)));
            acc.z=fmaf(x0,wx0.z,fmaf(x1,wx1.z,fmaf(x2,wx2.z,bb.z)));
            acc.w=fmaf(x0,wx0.w,fmaf(x1,wx1.w,fmaf(x2,wx2.w,bb.w)));
            const float4* wp=Wh4+g;
            #pragma unroll 8
            for(int k=0;k<UNITS;++k){
                const float hk=hsh[k]; const float4 w=wp[(size_t)k*400];
                acc.x=fmaf(hk,w.x,acc.x); acc.y=fmaf(hk,w.y,acc.y);
                acc.z=fmaf(hk,w.z,acc.z); acc.w=fmaf(hk,w.w,acc.w);
            }
            ((float4*)zsh)[g]=acc;
        }
        __syncthreads();
        float s0=0.f,s1=0.f,s2=0.f;
        if (tid<UNITS){
            const float cc=csh[tid];
            const float zi=zsh[tid],zf=zsh[tid+UNITS],zg=zsh[tid+2*UNITS],zo=zsh[tid+3*UNITS];
            const float ig=sigmoid_(fmaf(piu,cc,zi));
            const float fg=sigmoid_(fmaf(pfu,cc,zf));
            const float gg=tanh_(zg);
            const float cn=fmaf(fg,cc,ig*gg);
            const float og=sigmoid_(fmaf(pou,cn,zo));
            const float hn=og*tanh_(cn);
            csh[tid]=cn; hsh[tid]=hn;
            s0=hn*wo0; s1=hn*wo1; s2=hn*wo2;
        }
        #pragma unroll
        for(int off=32;off;off>>=1){
            s0+=__shfl_down(s0,off); s1+=__shfl_down(s1,off); s2+=__shfl_down(s2,off);
        }
        if(lane==0){red[wv][0]=s0;red[wv][1]=s1;red[wv][2]=s2;}
        __syncthreads();
        if(tid<3){
            float r=bo;
            #pragma unroll
            for(int w2=0;w2<8;++w2) r+=red[w2][tid];
            orow[t*3+tid]=r;
        }
    }
}

extern "C" void kernel_launch(void* const* d_in, const int* in_sizes, int n_in,
                              void* d_out, int out_size, void* d_ws, size_t ws_size,
                              hipStream_t stream) {
    const float* x     = (const float*)d_in[0];
    const float* W_x   = (const float*)d_in[1];
    const float* W_h   = (const float*)d_in[2];
    const float* b     = (const float*)d_in[3];
    const float* p_i   = (const float*)d_in[4];
    const float* p_f   = (const float*)d_in[5];
    const float* p_o   = (const float*)d_in[6];
    const float* W_out = (const float*)d_in[7];
    const float* b_out = (const float*)d_in[8];
    float* out = (float*)d_out;

    if (ws_size < WS_FULL) {
        lstm_fused_fb<<<BATCH, 512, 0, stream>>>(x, W_x, W_h, b, p_i, p_f, p_o,
                                                 W_out, b_out, out);
        return;
    }

    uint8_t* ws = (uint8_t*)d_ws;
    float* wbuf = (float*)(ws + WBUF_OFF);
    unsigned long long* hbuf = (unsigned long long*)(ws + HBUF_OFF);
    float* part = (float*)(ws + PART_OFF);

    hipMemsetAsync(hbuf, 0, HBUF_SZ, stream);    // kill stale tags (graph replay)
    reorder_w<<<(NBLK * UNITS * CPB + 255) / 256, 256, 0, stream>>>(W_h, wbuf);
    lstm_mb<<<NGRP * NBLK, 512, 0, stream>>>(x, W_x, b, p_i, p_f, p_o,
                                             W_out, wbuf, hbuf, part, out);
    finish_y<<<(BATCH * TLEN * 3 + 255) / 256, 256, 0, stream>>>(part, b_out, out);
}

// Round 8
// 2980.816 us; speedup vs baseline: 6.8488x; 1.0173x over previous
//
#include <hip/hip_runtime.h>
#include <hip/hip_bf16.h>
#include <stdint.h>

#define UNITS 400
#define GATES 1600
#define TLEN  1000
#define BATCH 64

#define NBLK 8         // blocks per group (weight slices)
#define NGRP 32        // groups
#define BPG  2         // batches per group
#define UPB  50        // units per block
#define CPB  200       // cols per block
#define KK   10        // k-split
#define KCH  40        // k-chunk -> 40x4 weight regs/thread (VGPR-pinned)

// d_ws layout
#define WBUF_OFF  0
#define WBUF_SZ   (NBLK*UNITS*CPB*4)                 // 2,560,000
#define HBUF_OFF  (WBUF_OFF + WBUF_SZ)
#define HBUF_SZ   (2*BATCH*UNITS*8)                  //   409,600 (u64 packets)
#define PART_OFF  (HBUF_OFF + HBUF_SZ)
#define PART_SZ   (NGRP*NBLK*BPG*3*TLEN*4)           // 6,144,000
#define WS_FULL   ((size_t)PART_OFF + PART_SZ)

__device__ __forceinline__ float sigmoid_(float x) {
    return 1.0f / (1.0f + __expf(-x));
}
__device__ __forceinline__ float tanh_(float x) {
    return 1.0f - 2.0f / (__expf(2.0f * x) + 1.0f);
}

// ---- one-time weight reorder: wbuf[j][k][c] = W_h[k][(c/UPB)*UNITS + j*UPB + c%UPB] ----
__global__ void reorder_w(const float* __restrict__ W_h, float* __restrict__ wbuf) {
    int i = blockIdx.x * 256 + threadIdx.x;
    if (i >= NBLK * UNITS * CPB) return;
    int c = i % CPB;
    int k = (i / CPB) % UNITS;
    int j = i / (CPB * UNITS);
    int g = c / UPB, u2 = c % UPB;
    int col = g * UNITS + j * UPB + u2;
    wbuf[i] = W_h[k * GATES + col];
}

// ---- main: VGPR-pinned weights, fused gates, tag-in-data exchange, 2 syncs/step ----
__global__ __launch_bounds__(512, 1) void lstm_mb(
    const float* __restrict__ x,      // [B,T,3]
    const float* __restrict__ W_x,    // [3,1600]
    const float* __restrict__ bvec,   // [1600]
    const float* __restrict__ p_i,
    const float* __restrict__ p_f,
    const float* __restrict__ p_o,
    const float* __restrict__ W_out,  // [400,3]
    const float* __restrict__ wbuf,
    unsigned long long* __restrict__ hbuf,   // [2][B][U] {tag,val}
    float*       __restrict__ part,          // [NGRP*NBLK][BPG][3][TLEN]
    float*       __restrict__ out)           // (finish_y writes out)
{
    const int gr  = blockIdx.x % NGRP;   // XCD-local heuristic (perf only)
    const int j   = blockIdx.x / NGRP;
    const int tid = threadIdx.x;

    __shared__ float hsh[BPG][UNITS];          // 3.2 KB
    __shared__ float zpart[KK][BPG][CPB];      // 16 KB
    __shared__ float wosh[UPB][3];
    __shared__ float xsh[BPG][4];

    const float* wslice = wbuf + (size_t)j * UNITS * CPB;

    // ---- roles ----
    const int kk = tid / 50, cq = tid % 50;       // z-role: tid < 500
    const bool zrole = (tid < KK * 50);
    const int k0 = kk * KCH;

    const int gb = tid / UPB, gu = tid % UPB;     // gate-role: tid < 100
    const bool grole = (tid < BPG * UPB);

    const bool prole = (tid < UNITS) && (tid / UPB != j);  // poll-role: skip own slice
    const bool yrole = (tid >= 500) && (tid < 500 + BPG * 3);
    const int yb = (tid - 500) / 3, yf = (tid - 500) % 3;
    const bool xrole = (tid >= 500 + BPG * 3) && (tid < 500 + 2 * BPG * 3);
    const int xb2 = (tid - 500 - BPG * 3) / 3, xf = (tid - 500 - BPG * 3) % 3;

    // ---- register-pinned weight patch: 40x4 floats, opaque to remat ----
    float wr[KCH][4];
    if (zrole) {
        #pragma unroll
        for (int r = 0; r < KCH; ++r) {
            const float4 w = *(const float4*)&wslice[(size_t)(k0 + r) * CPB + cq * 4];
            wr[r][0] = w.x; wr[r][1] = w.y; wr[r][2] = w.z; wr[r][3] = w.w;
        }
        #pragma unroll
        for (int r = 0; r < KCH; ++r) {
            asm volatile("" : "+v"(wr[r][0]), "+v"(wr[r][1]),
                              "+v"(wr[r][2]), "+v"(wr[r][3]));
        }
    }

    // ---- gate-thread hoists ----
    int unit = 0, batch = 0;
    float wxr[3][4], bb[4];
    float piu = 0.f, pfu = 0.f, pou = 0.f, cc = 0.f;
    if (grole) {
        unit  = j * UPB + gu;
        batch = gr * BPG + gb;
        #pragma unroll
        for (int g = 0; g < 4; ++g) {
            const int gcol = g * UNITS + unit;
            wxr[0][g] = W_x[0 * GATES + gcol];
            wxr[1][g] = W_x[1 * GATES + gcol];
            wxr[2][g] = W_x[2 * GATES + gcol];
            bb[g]     = bvec[gcol];
        }
        piu = p_i[unit]; pfu = p_f[unit]; pou = p_o[unit];
    }
    if (tid < UPB * 3) wosh[tid / 3][tid % 3] = W_out[(j * UPB + tid / 3) * 3 + (tid % 3)];

    // ---- state init ----
    if (tid < UNITS) { hsh[0][tid] = 0.f; hsh[1][tid] = 0.f; }
    __syncthreads();

    for (int t = 0; t < TLEN; ++t) {
        const int p = t & 1;

        // ================= A: z-partials (+ x stage, deferred partial-y) ========
        if (zrole) {
            float4 a0 = {0,0,0,0}, a1 = a0;
            #pragma unroll
            for (int ro = 0; ro < KCH; ro += 4) {
                const float4 h0 = *(const float4*)&hsh[0][k0 + ro];
                const float4 h1 = *(const float4*)&hsh[1][k0 + ro];
                #pragma unroll
                for (int dr = 0; dr < 4; ++dr) {
                    const float e0 = (dr==0)?h0.x:(dr==1)?h0.y:(dr==2)?h0.z:h0.w;
                    const float e1 = (dr==0)?h1.x:(dr==1)?h1.y:(dr==2)?h1.z:h1.w;
                    a0.x = fmaf(e0, wr[ro+dr][0], a0.x);
                    a0.y = fmaf(e0, wr[ro+dr][1], a0.y);
                    a0.z = fmaf(e0, wr[ro+dr][2], a0.z);
                    a0.w = fmaf(e0, wr[ro+dr][3], a0.w);
                    a1.x = fmaf(e1, wr[ro+dr][0], a1.x);
                    a1.y = fmaf(e1, wr[ro+dr][1], a1.y);
                    a1.z = fmaf(e1, wr[ro+dr][2], a1.z);
                    a1.w = fmaf(e1, wr[ro+dr][3], a1.w);
                }
            }
            *(float4*)&zpart[kk][0][cq * 4] = a0;
            *(float4*)&zpart[kk][1][cq * 4] = a1;
        } else if (yrole && t > 0) {
            // y partial for step t-1 (hsh holds that step's output h)
            float s = 0.f;
            #pragma unroll
            for (int u = 0; u < UPB; ++u)
                s += hsh[yb][j * UPB + u] * wosh[u][yf];
            part[(((size_t)(gr * NBLK + j) * BPG + yb) * 3 + yf) * TLEN + (t - 1)] = s;
        } else if (xrole) {
            xsh[xb2][xf] = x[((size_t)(gr * BPG + xb2) * TLEN + t) * 3 + xf];
        }
        __syncthreads();   // zpart + xsh ready; hsh reads done

        // ================= B: fused reduce + gates + publish (tid<100) ==========
        if (grole) {
            const float x0 = xsh[gb][0], x1 = xsh[gb][1], x2 = xsh[gb][2];
            float s[4];
            #pragma unroll
            for (int g = 0; g < 4; ++g) {
                float acc = fmaf(x0, wxr[0][g],
                            fmaf(x1, wxr[1][g],
                            fmaf(x2, wxr[2][g], bb[g])));
                #pragma unroll
                for (int q = 0; q < KK; ++q) acc += zpart[q][gb][g * UPB + gu];
                s[g] = acc;
            }
            const float ig = sigmoid_(fmaf(piu, cc, s[0]));
            const float fg = sigmoid_(fmaf(pfu, cc, s[1]));
            const float gg = tanh_(s[2]);
            const float cn = fmaf(fg, cc, ig * gg);
            const float og = sigmoid_(fmaf(pou, cn, s[3]));
            const float hn = og * tanh_(cn);
            cc = cn;
            hsh[gb][unit] = hn;    // own slice locally
            const unsigned long long pkt =
                ((unsigned long long)(unsigned)(t + 1) << 32) |
                (unsigned long long)__float_as_uint(hn);
            __hip_atomic_store(&hbuf[(size_t)p * BATCH * UNITS + (size_t)batch * UNITS + unit],
                               pkt, __ATOMIC_RELAXED, __HIP_MEMORY_SCOPE_AGENT);
        }

        // ================= C: poll remote slices (overlaps B) ===================
        if (prole) {
            const unsigned want = (unsigned)(t + 1);
            const size_t base = (size_t)p * BATCH * UNITS
                              + (size_t)(gr * BPG) * UNITS + tid;
            unsigned long long v0, v1;
            for (;;) {
                v0 = __hip_atomic_load(&hbuf[base],
                                       __ATOMIC_RELAXED, __HIP_MEMORY_SCOPE_AGENT);
                v1 = __hip_atomic_load(&hbuf[base + UNITS],
                                       __ATOMIC_RELAXED, __HIP_MEMORY_SCOPE_AGENT);
                if ((unsigned)(v0 >> 32) == want && (unsigned)(v1 >> 32) == want) break;
                __builtin_amdgcn_s_sleep(2);
            }
            hsh[0][tid] = __uint_as_float((unsigned)v0);
            hsh[1][tid] = __uint_as_float((unsigned)v1);
        }
        __syncthreads();   // hsh = h_{t+1} complete
    }

    // ---- epilogue: y partial for final step ----
    if (yrole) {
        float s = 0.f;
        #pragma unroll
        for (int u = 0; u < UPB; ++u)
            s += hsh[yb][j * UPB + u] * wosh[u][yf];
        part[(((size_t)(gr * NBLK + j) * BPG + yb) * 3 + yf) * TLEN + (TLEN - 1)] = s;
    }
}

// ---- post-kernel: out[b][t][f] = b_out[f] + sum_j part[gr][j][gb][f][t] ----
__global__ void finish_y(const float* __restrict__ part,
                         const float* __restrict__ b_out,
                         float* __restrict__ out) {
    int i = blockIdx.x * 256 + threadIdx.x;
    if (i >= BATCH * TLEN * 3) return;
    const int f = i % 3;
    const int bt = i / 3;
    const int t = bt % TLEN;
    const int b = bt / TLEN;
    const int gr = b / BPG, gb = b % BPG;
    float s = b_out[f];
    #pragma unroll
    for (int j = 0; j < NBLK; ++j)
        s += part[(((size_t)(gr * NBLK + j) * BPG + gb) * 3 + f) * TLEN + t];
    out[i] = s;
}

// ---- fallback: proven round-1 single-block-per-batch kernel ----
__global__ __launch_bounds__(512) void lstm_fused_fb(
    const float* __restrict__ x, const float* __restrict__ W_x,
    const float* __restrict__ W_h, const float* __restrict__ bvec,
    const float* __restrict__ p_i, const float* __restrict__ p_f,
    const float* __restrict__ p_o, const float* __restrict__ W_out,
    const float* __restrict__ b_out, float* __restrict__ out)
{
    const int b = blockIdx.x, tid = threadIdx.x;
    const int lane = tid & 63, wv = tid >> 6;
    __shared__ float hsh[UNITS], csh[UNITS], zsh[GATES], xb[3], red[8][3];
    const float4* Wh4 = (const float4*)W_h;
    const int g = tid;
    float4 wx0, wx1, wx2, bb;
    if (g < GATES/4) {
        const float4* Wx4 = (const float4*)W_x;
        wx0 = Wx4[0*400 + g]; wx1 = Wx4[1*400 + g]; wx2 = Wx4[2*400 + g];
        bb  = ((const float4*)bvec)[g];
    }
    float piu=0.f,pfu=0.f,pou=0.f,wo0=0.f,wo1=0.f,wo2=0.f;
    if (tid < UNITS) {
        piu=p_i[tid]; pfu=p_f[tid]; pou=p_o[tid];
        wo0=W_out[tid*3]; wo1=W_out[tid*3+1]; wo2=W_out[tid*3+2];
        hsh[tid]=0.f; csh[tid]=0.f;
    }
    const float bo = (tid<3)?b_out[tid]:0.f;
    const float* xrow = x + (size_t)b*TLEN*3;
    float* orow = out + (size_t)b*TLEN*3;
    for (int t=0;t<TLEN;++t){
        if (tid<3) xb[tid]=xrow[t*3+tid];
        __syncthreads();
        const float x0=xb[0],x1=xb[1],x2=xb[2];
        if (g < GATES/4){
            float4 acc;
            acc.x=fmaf(x0,wx0.x,fmaf(x1,wx1.x,fmaf(x2,wx2.x,bb.x)));
            acc.y=fmaf(x0,wx0.y,fmaf(x1,wx1.y,fmaf(x2,wx2.y,bb.y)));
            acc.z=fmaf(x0,wx0.z,fmaf(x1,wx1.z,fmaf(x2,wx2.z,bb.z)));
            acc.w=fmaf(x0,wx0.w,fmaf(x1,wx1.w,fmaf(x2,wx2.w,bb.w)));
            const float4* wp=Wh4+g;
            #pragma unroll 8
            for(int k=0;k<UNITS;++k){
                const float hk=hsh[k]; const float4 w=wp[(size_t)k*400];
                acc.x=fmaf(hk,w.x,acc.x); acc.y=fmaf(hk,w.y,acc.y);
                acc.z=fmaf(hk,w.z,acc.z); acc.w=fmaf(hk,w.w,acc.w);
            }
            ((float4*)zsh)[g]=acc;
        }
        __syncthreads();
        float s0=0.f,s1=0.f,s2=0.f;
        if (tid<UNITS){
            const float cc=csh[tid];
            const float zi=zsh[tid],zf=zsh[tid+UNITS],zg=zsh[tid+2*UNITS],zo=zsh[tid+3*UNITS];
            const float ig=sigmoid_(fmaf(piu,cc,zi));
            const float fg=sigmoid_(fmaf(pfu,cc,zf));
            const float gg=tanh_(zg);
            const float cn=fmaf(fg,cc,ig*gg);
            const float og=sigmoid_(fmaf(pou,cn,zo));
            const float hn=og*tanh_(cn);
            csh[tid]=cn; hsh[tid]=hn;
            s0=hn*wo0; s1=hn*wo1; s2=hn*wo2;
        }
        #pragma unroll
        for(int off=32;off;off>>=1){
            s0+=__shfl_down(s0,off); s1+=__shfl_down(s1,off); s2+=__shfl_down(s2,off);
        }
        if(lane==0){red[wv][0]=s0;red[wv][1]=s1;red[wv][2]=s2;}
        __syncthreads();
        if(tid<3){
            float r=bo;
            #pragma unroll
            for(int w2=0;w2<8;++w2) r+=red[w2][tid];
            orow[t*3+tid]=r;
        }
    }
}

extern "C" void kernel_launch(void* const* d_in, const int* in_sizes, int n_in,
                              void* d_out, int out_size, void* d_ws, size_t ws_size,
                              hipStream_t stream) {
    const float* x     = (const float*)d_in[0];
    const float* W_x   = (const float*)d_in[1];
    const float* W_h   = (const float*)d_in[2];
    const float* b     = (const float*)d_in[3];
    const float* p_i   = (const float*)d_in[4];
    const float* p_f   = (const float*)d_in[5];
    const float* p_o   = (const float*)d_in[6];
    const float* W_out = (const float*)d_in[7];
    const float* b_out = (const float*)d_in[8];
    float* out = (float*)d_out;

    if (ws_size < WS_FULL) {
        lstm_fused_fb<<<BATCH, 512, 0, stream>>>(x, W_x, W_h, b, p_i, p_f, p_o,
                                                 W_out, b_out, out);
        return;
    }

    uint8_t* ws = (uint8_t*)d_ws;
    float* wbuf = (float*)(ws + WBUF_OFF);
    unsigned long long* hbuf = (unsigned long long*)(ws + HBUF_OFF);
    float* part = (float*)(ws + PART_OFF);

    hipMemsetAsync(hbuf, 0, HBUF_SZ, stream);    // kill stale tags (graph replay)
    reorder_w<<<(NBLK * UNITS * CPB + 255) / 256, 256, 0, stream>>>(W_h, wbuf);
    lstm_mb<<<NGRP * NBLK, 512, 0, stream>>>(x, W_x, b, p_i, p_f, p_o,
                                             W_out, wbuf, hbuf, part, out);
    finish_y<<<(BATCH * TLEN * 3 + 255) / 256, 256, 0, stream>>>(part, b_out, out);
}